// Round 2
// baseline (623.777 us; speedup 1.0000x reference)
//
#include <hip/hip_runtime.h>

// ---------------------------------------------------------------------------
// Attention_16698832847178: B=2,S=2048,D=2048,H=16,HD=128,L=10
// R2: flash restructured to 128-thread blocks / q-tile 64 -> 40KB LDS ->
// 4 independent blocks/CU (latency hiding + finer balance); QKV GEMMs fused
// into one dispatch over the contiguous WtQ|WtK|WtV buffer.
// ---------------------------------------------------------------------------

typedef unsigned short ushort_t;
typedef unsigned int uint32;
typedef __attribute__((ext_vector_type(8))) short bf16x8;   // 8 bf16 = 4 VGPRs
typedef __attribute__((ext_vector_type(4))) float f32x4;

__device__ __forceinline__ void async16(void* lds, const void* g) {
  // global -> LDS direct copy, 16B per lane; LDS dest = uniform base + lane*16
  __builtin_amdgcn_global_load_lds((const __attribute__((address_space(1))) void*)g,
                                   (__attribute__((address_space(3))) void*)lds,
                                   16, 0, 0);
}
__device__ __forceinline__ ushort_t f2bf(float f) {
  uint32 u = __float_as_uint(f);
  u += 0x7FFFu + ((u >> 16) & 1u);   // round-to-nearest-even
  return (ushort_t)(u >> 16);
}
__device__ __forceinline__ float bf2f(ushort_t b) {
  return __uint_as_float(((uint32)b) << 16);
}

// ---------------------------------------------------------------------------
// cast x (fp32) -> bf16, 8 elements/thread
__global__ __launch_bounds__(256) void cast_x_kernel(const float* __restrict__ x,
                                                     ushort_t* __restrict__ Xb) {
  size_t i = ((size_t)blockIdx.x * 256 + threadIdx.x) * 8;
  float4 a = *(const float4*)(x + i);
  float4 b = *(const float4*)(x + i + 4);
  uint4 o;
  o.x = (uint32)f2bf(a.x) | ((uint32)f2bf(a.y) << 16);
  o.y = (uint32)f2bf(a.z) | ((uint32)f2bf(a.w) << 16);
  o.z = (uint32)f2bf(b.x) | ((uint32)f2bf(b.y) << 16);
  o.w = (uint32)f2bf(b.z) | ((uint32)f2bf(b.w) << 16);
  *(uint4*)(Xb + i) = o;
}

// ---------------------------------------------------------------------------
// W[k][n] fp32 -> Wt[n][k] bf16 (64x64 tiles)
__global__ __launch_bounds__(256) void transpose_w_kernel(
    const float* __restrict__ w0, const float* __restrict__ w1,
    const float* __restrict__ w2, const float* __restrict__ w3,
    ushort_t* __restrict__ outBase) {
  const float* W = (blockIdx.z == 0) ? w0 : (blockIdx.z == 1) ? w1
                 : (blockIdx.z == 2) ? w2 : w3;
  ushort_t* Wt = outBase + (size_t)blockIdx.z * 4194304;  // 2048*2048
  __shared__ float L[64][65];
  int t = threadIdx.x, tc = t & 63, tr = t >> 6;
  int k0 = blockIdx.x * 64, n0 = blockIdx.y * 64;
  for (int i = 0; i < 16; ++i) {
    int r = i * 4 + tr;
    L[r][tc] = W[(size_t)(k0 + r) * 2048 + n0 + tc];
  }
  __syncthreads();
  for (int i = 0; i < 16; ++i) {
    int r = i * 4 + tr;
    Wt[(size_t)(n0 + r) * 2048 + k0 + tc] = f2bf(L[tc][r]);
  }
}

// ---------------------------------------------------------------------------
// Vb (B,S,H,HD) bf16 -> Vt (B,H,HD,S) bf16
__global__ __launch_bounds__(256) void transpose_v_kernel(
    const ushort_t* __restrict__ Vb, ushort_t* __restrict__ Vt) {
  __shared__ ushort_t L[64][65];
  int t = threadIdx.x, tc = t & 63, tr = t >> 6;
  int s0 = blockIdx.x * 64, d0 = blockIdx.y * 64;
  int bh = blockIdx.z, b = bh >> 4, h = bh & 15;
  for (int i = 0; i < 16; ++i) {
    int r = i * 4 + tr;
    L[r][tc] = Vb[((size_t)b * 2048 + s0 + r) * 2048 + h * 128 + d0 + tc];
  }
  __syncthreads();
  for (int i = 0; i < 16; ++i) {
    int r = i * 4 + tr;
    Vt[((size_t)bh * 128 + d0 + r) * 2048 + s0 + tc] = L[tc][r];
  }
}

// ---------------------------------------------------------------------------
// adapter projections: ak/av[l][n] = sum_k adapter[l][k] * W[k][n]  (fp32)
__global__ __launch_bounds__(256) void adapter_kv_kernel(
    const float* __restrict__ adapter, const float* __restrict__ wk,
    const float* __restrict__ wv, float* __restrict__ ak, float* __restrict__ av) {
  const float* W = blockIdx.z ? wv : wk;
  float* out = blockIdx.z ? av : ak;
  __shared__ float As[10][128];
  int t = threadIdx.x;
  int k0 = blockIdx.y * 128;
  for (int i = t; i < 1280; i += 256)
    As[i >> 7][i & 127] = adapter[(size_t)(i >> 7) * 2048 + k0 + (i & 127)];
  __syncthreads();
  int n = blockIdx.x * 256 + t;
  float acc[10];
#pragma unroll
  for (int l = 0; l < 10; ++l) acc[l] = 0.f;
  for (int kk = 0; kk < 128; ++kk) {
    float wv_ = W[(size_t)(k0 + kk) * 2048 + n];
#pragma unroll
    for (int l = 0; l < 10; ++l) acc[l] += As[l][kk] * wv_;
  }
#pragma unroll
  for (int l = 0; l < 10; ++l) atomicAdd(&out[l * 2048 + n], acc[l]);
}

// ---------------------------------------------------------------------------
// Fused QKV GEMM: C[4096, 6144] = Xb[4096,2048] x WtQKV[6144,2048]^T.
// Per-block output segment (Q/K/V) chosen by global col; RoPE fused for Q,K.
__global__ __launch_bounds__(256) void gemm_qkv_kernel(
    const ushort_t* __restrict__ A, const ushort_t* __restrict__ Bt,
    ushort_t* __restrict__ outQ, ushort_t* __restrict__ outK,
    ushort_t* __restrict__ outV,
    const float* __restrict__ fc, const float* __restrict__ fs) {
  __shared__ char ldsA[16384];
  __shared__ char ldsB[16384];
  const int tid = threadIdx.x;
  const int w = tid >> 6, lane = tid & 63, quad = lane >> 4, l15 = lane & 15;
  const int wm = (w >> 1) * 64, wn = (w & 1) * 64;
  const size_t bm0 = (size_t)blockIdx.y * 128, bn0 = (size_t)blockIdx.x * 128;
  const int K = 2048;

  f32x4 zero4 = {0.f, 0.f, 0.f, 0.f};
  f32x4 acc[4][4];
#pragma unroll
  for (int i = 0; i < 4; ++i)
#pragma unroll
    for (int j = 0; j < 4; ++j) acc[i][j] = zero4;

  const int rS = w * 32;
  const int rowOff = lane >> 3;
  const int cph = lane & 7;

  for (int kt = 0; kt < K; kt += 64) {
#pragma unroll
    for (int i = 0; i < 4; ++i) {
      int r0 = rS + i * 8;
      int row = r0 + rowOff;
      int cl = cph ^ (row & 7);
      async16(ldsA + r0 * 128, A + (bm0 + row) * (size_t)K + kt + cl * 8);
      async16(ldsB + r0 * 128, Bt + (bn0 + row) * (size_t)K + kt + cl * 8);
    }
    __syncthreads();
#pragma unroll
    for (int ks = 0; ks < 2; ++ks) {
      bf16x8 af[4], bfv[4];
      int ch = ks * 4 + quad;
#pragma unroll
      for (int tt = 0; tt < 4; ++tt) {
        int ra = wm + tt * 16 + l15;
        af[tt] = *(const bf16x8*)(ldsA + ra * 128 + ((ch ^ (ra & 7)) * 16));
        int rb = wn + tt * 16 + l15;
        bfv[tt] = *(const bf16x8*)(ldsB + rb * 128 + ((ch ^ (rb & 7)) * 16));
      }
#pragma unroll
      for (int i = 0; i < 4; ++i)
#pragma unroll
        for (int j = 0; j < 4; ++j)
          acc[i][j] = __builtin_amdgcn_mfma_f32_16x16x32_bf16(af[i], bfv[j], acc[i][j], 0, 0, 0);
    }
    __syncthreads();
  }

  const int seg = (int)(bn0 >> 11);           // 0=Q, 1=K, 2=V
  ushort_t* ob = (seg == 0) ? outQ : (seg == 1) ? outK : outV;
  const bool rope = (seg < 2);
#pragma unroll
  for (int i = 0; i < 4; ++i)
#pragma unroll
    for (int r = 0; r < 4; ++r) {
      size_t m = bm0 + wm + i * 16 + quad * 4 + r;
      int s = (int)(m & 2047);
#pragma unroll
      for (int j = 0; j < 4; ++j) {
        size_t ngl = bn0 + wn + j * 16 + l15;
        size_t n = ngl & 2047;
        float v = acc[i][j][r];
        if (rope) {
          float v2 = __shfl_xor(v, 1, 64);    // RoPE pair partner (col n^1)
          int fi = ((int)n & 127) >> 1;
          float c = fc[s * 64 + fi], sn = fs[s * 64 + fi];
          v = (lane & 1) ? (v2 * sn + v * c) : (v * c - v2 * sn);
        }
        ob[m * 2048 + n] = f2bf(v);
      }
    }
}

// ---------------------------------------------------------------------------
// Generic GEMM (fp32 out) for the output projection.
__global__ __launch_bounds__(256) void gemm_kernel(
    const ushort_t* __restrict__ A, const ushort_t* __restrict__ Bt,
    float* __restrict__ out, int M, int N, int K) {
  __shared__ char ldsA[16384];
  __shared__ char ldsB[16384];
  const int tid = threadIdx.x;
  const int w = tid >> 6, lane = tid & 63, quad = lane >> 4, l15 = lane & 15;
  const int wm = (w >> 1) * 64, wn = (w & 1) * 64;
  const size_t bm0 = (size_t)blockIdx.y * 128, bn0 = (size_t)blockIdx.x * 128;

  f32x4 zero4 = {0.f, 0.f, 0.f, 0.f};
  f32x4 acc[4][4];
#pragma unroll
  for (int i = 0; i < 4; ++i)
#pragma unroll
    for (int j = 0; j < 4; ++j) acc[i][j] = zero4;

  const int rS = w * 32;
  const int rowOff = lane >> 3;
  const int cph = lane & 7;

  for (int kt = 0; kt < K; kt += 64) {
#pragma unroll
    for (int i = 0; i < 4; ++i) {
      int r0 = rS + i * 8;
      int row = r0 + rowOff;
      int cl = cph ^ (row & 7);
      async16(ldsA + r0 * 128, A + (bm0 + row) * (size_t)K + kt + cl * 8);
      async16(ldsB + r0 * 128, Bt + (bn0 + row) * (size_t)K + kt + cl * 8);
    }
    __syncthreads();
#pragma unroll
    for (int ks = 0; ks < 2; ++ks) {
      bf16x8 af[4], bfv[4];
      int ch = ks * 4 + quad;
#pragma unroll
      for (int tt = 0; tt < 4; ++tt) {
        int ra = wm + tt * 16 + l15;
        af[tt] = *(const bf16x8*)(ldsA + ra * 128 + ((ch ^ (ra & 7)) * 16));
        int rb = wn + tt * 16 + l15;
        bfv[tt] = *(const bf16x8*)(ldsB + rb * 128 + ((ch ^ (rb & 7)) * 16));
      }
#pragma unroll
      for (int i = 0; i < 4; ++i)
#pragma unroll
        for (int j = 0; j < 4; ++j)
          acc[i][j] = __builtin_amdgcn_mfma_f32_16x16x32_bf16(af[i], bfv[j], acc[i][j], 0, 0, 0);
    }
    __syncthreads();
  }
#pragma unroll
  for (int i = 0; i < 4; ++i)
#pragma unroll
    for (int r = 0; r < 4; ++r) {
      size_t m = bm0 + wm + i * 16 + quad * 4 + r;
#pragma unroll
      for (int j = 0; j < 4; ++j) {
        size_t n = bn0 + wn + j * 16 + l15;
        out[m * N + n] = acc[i][j][r];
      }
    }
}

// ---------------------------------------------------------------------------
// Flash attention, causal. 128 threads (2 waves), q-tile 64 (wave: 32 rows),
// k-tile 64. LDS = 16K (K) + 16K (V^T) + 8K (P) = 40KB -> 4 blocks/CU.
// qt = heavy/light interleave over 32 q-tiles.
__global__ __launch_bounds__(128) void flash_kernel(
    const ushort_t* __restrict__ Qb, const ushort_t* __restrict__ Kb,
    const ushort_t* __restrict__ Vt, float* __restrict__ O) {
  __shared__ char ldsK[16384];   // 64 tok x 256B, chunk swz ^(row&15)
  __shared__ char ldsV[16384];   // 128 d x 128B, chunk swz ^(row&7)
  __shared__ char ldsP[8192];    // 64 q x 128B, chunk swz ^(row&7)
  const int tid = threadIdx.x;
  const int w = tid >> 6, lane = tid & 63, quad = lane >> 4, l15 = lane & 15;
  const int bx = blockIdx.x;
  const int qt = (bx & 1) ? (31 - (bx >> 1)) : (bx >> 1);  // heavy/light pairing
  const int h = blockIdx.y, b = blockIdx.z;
  const float scale = 0.08838834764831845f;  // 1/sqrt(128)

  // Q fragments in registers: 2 m-tiles x 4 d-steps
  bf16x8 qf[2][4];
#pragma unroll
  for (int mt = 0; mt < 2; ++mt) {
    size_t qrow = (size_t)qt * 64 + w * 32 + mt * 16 + l15;
    const ushort_t* base = Qb + ((size_t)b * 2048 + qrow) * 2048 + h * 128 + quad * 8;
#pragma unroll
    for (int ds = 0; ds < 4; ++ds) qf[mt][ds] = *(const bf16x8*)(base + ds * 32);
  }

  f32x4 zero4 = {0.f, 0.f, 0.f, 0.f};
  f32x4 oacc[2][8];
  float mrow[2][4], lrow[2][4];
#pragma unroll
  for (int mt = 0; mt < 2; ++mt) {
#pragma unroll
    for (int n8 = 0; n8 < 8; ++n8) oacc[mt][n8] = zero4;
#pragma unroll
    for (int r = 0; r < 4; ++r) { mrow[mt][r] = -1e30f; lrow[mt][r] = 0.f; }
  }

  for (int kt = 0; kt <= qt; ++kt) {
    // stage K-tile: wave w covers rows w*32..w*32+31 (8 instrs x 4 rows)
#pragma unroll
    for (int i = 0; i < 8; ++i) {
      int r0 = w * 32 + i * 4;
      int row = r0 + (lane >> 4);
      int cl = (lane & 15) ^ (row & 15);
      async16(ldsK + r0 * 256,
              Kb + ((size_t)b * 2048 + kt * 64 + row) * 2048 + h * 128 + cl * 8);
    }
    // stage V^T-tile: wave w covers d-rows w*64..w*64+63 (8 instrs x 8 rows)
#pragma unroll
    for (int i = 0; i < 8; ++i) {
      int d0 = w * 64 + i * 8;
      int dr = d0 + (lane >> 3);
      int cl = (lane & 7) ^ (dr & 7);
      async16(ldsV + d0 * 128,
              Vt + ((size_t)(b * 16 + h) * 128 + dr) * 2048 + kt * 64 + cl * 8);
    }
    __syncthreads();

    // S = Q K^T
    f32x4 sacc[2][4];
#pragma unroll
    for (int mt = 0; mt < 2; ++mt)
#pragma unroll
      for (int nt = 0; nt < 4; ++nt) sacc[mt][nt] = zero4;
#pragma unroll
    for (int ds = 0; ds < 4; ++ds) {
      bf16x8 kf[4];
      int ch = ds * 4 + quad;
#pragma unroll
      for (int nt = 0; nt < 4; ++nt) {
        int row = nt * 16 + l15;
        kf[nt] = *(const bf16x8*)(ldsK + row * 256 + ((ch ^ (row & 15)) * 16));
      }
#pragma unroll
      for (int mt = 0; mt < 2; ++mt)
#pragma unroll
        for (int nt = 0; nt < 4; ++nt)
          sacc[mt][nt] = __builtin_amdgcn_mfma_f32_16x16x32_bf16(qf[mt][ds], kf[nt], sacc[mt][nt], 0, 0, 0);
    }

    // online softmax
    const bool domask = (kt == qt);
#pragma unroll
    for (int mt = 0; mt < 2; ++mt) {
      float tmax[4] = {-1e30f, -1e30f, -1e30f, -1e30f};
      const int qbase = qt * 64 + w * 32 + mt * 16 + quad * 4;
#pragma unroll
      for (int nt = 0; nt < 4; ++nt) {
        int kg = kt * 64 + nt * 16 + l15;
#pragma unroll
        for (int r = 0; r < 4; ++r) {
          float s = sacc[mt][nt][r] * scale;
          if (domask && kg > qbase + r) s = -1e30f;
          sacc[mt][nt][r] = s;
          tmax[r] = fmaxf(tmax[r], s);
        }
      }
#pragma unroll
      for (int r = 0; r < 4; ++r) {
        float t = tmax[r];
        t = fmaxf(t, __shfl_xor(t, 1, 64));
        t = fmaxf(t, __shfl_xor(t, 2, 64));
        t = fmaxf(t, __shfl_xor(t, 4, 64));
        t = fmaxf(t, __shfl_xor(t, 8, 64));
        float mnew = fmaxf(mrow[mt][r], t);
        float alpha = __expf(mrow[mt][r] - mnew);
        mrow[mt][r] = mnew;
        lrow[mt][r] *= alpha;
#pragma unroll
        for (int n8 = 0; n8 < 8; ++n8) oacc[mt][n8][r] *= alpha;
        tmax[r] = mnew;
      }
      float tsum[4] = {0.f, 0.f, 0.f, 0.f};
#pragma unroll
      for (int nt = 0; nt < 4; ++nt)
#pragma unroll
        for (int r = 0; r < 4; ++r) {
          float p = __expf(sacc[mt][nt][r] - tmax[r]);
          sacc[mt][nt][r] = p;
          tsum[r] += p;
        }
#pragma unroll
      for (int r = 0; r < 4; ++r) {
        float t = tsum[r];
        t += __shfl_xor(t, 1, 64);
        t += __shfl_xor(t, 2, 64);
        t += __shfl_xor(t, 4, 64);
        t += __shfl_xor(t, 8, 64);
        lrow[mt][r] += t;
      }
      // P (C-layout) -> LDS (A-layout readable), bf16; per-wave private rows
#pragma unroll
      for (int nt = 0; nt < 4; ++nt) {
        int col = nt * 16 + l15;
#pragma unroll
        for (int r = 0; r < 4; ++r) {
          int prow = w * 32 + mt * 16 + quad * 4 + r;
          int addr = prow * 128 + (((col >> 3) ^ (prow & 7)) * 16) + (col & 7) * 2;
          *(ushort_t*)(ldsP + addr) = f2bf(sacc[mt][nt][r]);
        }
      }
    }

    // O += P V
#pragma unroll
    for (int ks = 0; ks < 2; ++ks) {
      int ch = ks * 4 + quad;
      bf16x8 pf[2];
#pragma unroll
      for (int mt = 0; mt < 2; ++mt) {
        int prow = w * 32 + mt * 16 + l15;
        pf[mt] = *(const bf16x8*)(ldsP + prow * 128 + ((ch ^ (prow & 7)) * 16));
      }
#pragma unroll
      for (int n8 = 0; n8 < 8; ++n8) {
        int dr = n8 * 16 + l15;
        bf16x8 vf = *(const bf16x8*)(ldsV + dr * 128 + ((ch ^ (dr & 7)) * 16));
#pragma unroll
        for (int mt = 0; mt < 2; ++mt)
          oacc[mt][n8] = __builtin_amdgcn_mfma_f32_16x16x32_bf16(pf[mt], vf, oacc[mt][n8], 0, 0, 0);
      }
    }
    __syncthreads();
  }

  // normalize + store O (B,S,H,HD) fp32
#pragma unroll
  for (int mt = 0; mt < 2; ++mt) {
    float rl[4];
#pragma unroll
    for (int r = 0; r < 4; ++r) rl[r] = 1.f / lrow[mt][r];
    size_t qb0 = (size_t)qt * 64 + w * 32 + mt * 16 + quad * 4;
#pragma unroll
    for (int n8 = 0; n8 < 8; ++n8) {
      size_t col = (size_t)h * 128 + n8 * 16 + l15;
#pragma unroll
      for (int r = 0; r < 4; ++r)
        O[((size_t)b * 2048 + qb0 + r) * 2048 + col] = oacc[mt][n8][r] * rl[r];
    }
  }
}

// ---------------------------------------------------------------------------
// adapter attention add + cast O fp32 -> bf16. One wave per (b,s,h).
__global__ __launch_bounds__(256) void adapter_add_kernel(
    const float* __restrict__ O, const ushort_t* __restrict__ Qb,
    const float* __restrict__ ak, const float* __restrict__ av,
    const float* __restrict__ gate, ushort_t* __restrict__ Ob) {
  const int w = threadIdx.x >> 6, lane = threadIdx.x & 63;
  const size_t idx = (size_t)blockIdx.x * 4 + w;   // (b*2048+s)*16 + h
  const int h = (int)(idx & 15);
  const size_t bs = idx >> 4;
  const size_t base = bs * 2048 + h * 128 + lane * 2;
  uint32 qraw = *(const uint32*)(Qb + base);
  float q0 = bf2f((ushort_t)(qraw & 0xFFFFu));
  float q1 = bf2f((ushort_t)(qraw >> 16));
  const float scale = 0.08838834764831845f;
  const int col = h * 128 + lane * 2;
  float sc[10];
#pragma unroll
  for (int l = 0; l < 10; ++l) {
    float2 a = *(const float2*)(ak + l * 2048 + col);
    float v = q0 * a.x + q1 * a.y;
    v += __shfl_xor(v, 32, 64);
    v += __shfl_xor(v, 16, 64);
    v += __shfl_xor(v, 8, 64);
    v += __shfl_xor(v, 4, 64);
    v += __shfl_xor(v, 2, 64);
    v += __shfl_xor(v, 1, 64);
    sc[l] = v * scale;
  }
  float mx = sc[0];
#pragma unroll
  for (int l = 1; l < 10; ++l) mx = fmaxf(mx, sc[l]);
  float e[10], sum = 0.f;
#pragma unroll
  for (int l = 0; l < 10; ++l) { e[l] = __expf(sc[l] - mx); sum += e[l]; }
  float g = gate[h] / sum;
  float o0 = 0.f, o1 = 0.f;
#pragma unroll
  for (int l = 0; l < 10; ++l) {
    float2 a = *(const float2*)(av + l * 2048 + col);
    o0 += e[l] * a.x;
    o1 += e[l] * a.y;
  }
  float r0 = O[base] + g * o0;
  float r1 = O[base + 1] + g * o1;
  *(uint32*)(Ob + base) = (uint32)f2bf(r0) | ((uint32)f2bf(r1) << 16);
}

// ---------------------------------------------------------------------------
extern "C" void kernel_launch(void* const* d_in, const int* in_sizes, int n_in,
                              void* d_out, int out_size, void* d_ws, size_t ws_size,
                              hipStream_t stream) {
  (void)in_sizes; (void)n_in; (void)out_size; (void)ws_size;
  const float* x       = (const float*)d_in[0];
  const float* wq      = (const float*)d_in[1];
  const float* wk      = (const float*)d_in[2];
  const float* wv      = (const float*)d_in[3];
  const float* wo      = (const float*)d_in[4];
  const float* adapter = (const float*)d_in[5];
  const float* gate    = (const float*)d_in[6];
  const float* fc      = (const float*)d_in[7];
  const float* fs      = (const float*)d_in[8];

  char* ws = (char*)d_ws;
  // workspace layout (134,381,568 bytes total)
  ushort_t* Xb  = (ushort_t*)(ws + 0);            // 16,777,216  (reused as Ob)
  ushort_t* WtQ = (ushort_t*)(ws + 16777216);     // 8,388,608 (WtQ|WtK|WtV|WtO contiguous)
  ushort_t* WtO = (ushort_t*)(ws + 41943040);
  ushort_t* Qb  = (ushort_t*)(ws + 50331648);     // 16,777,216
  ushort_t* Kb  = (ushort_t*)(ws + 67108864);     // 16,777,216
  ushort_t* Vt  = (ushort_t*)(ws + 83886080);     // 16,777,216
  float*    O   = (float*)   (ws + 100663296);    // 33,554,432
  ushort_t* Vb  = (ushort_t*)(ws + 100663296);    // temp (first half of O region)
  float*    ak  = (float*)   (ws + 134217728);    // 81,920
  float*    av  = (float*)   (ws + 134299648);    // 81,920
  ushort_t* Ob  = Xb;                             // reuse: Xb dead after QKV GEMM

  cast_x_kernel<<<4096, 256, 0, stream>>>(x, Xb);
  transpose_w_kernel<<<dim3(32, 32, 4), 256, 0, stream>>>(wq, wk, wv, wo, WtQ);
  hipMemsetAsync(ak, 0, 163840, stream);
  adapter_kv_kernel<<<dim3(8, 16, 2), 256, 0, stream>>>(adapter, wk, wv, ak, av);
  // fused QKV projection (RoPE fused for Q,K)
  gemm_qkv_kernel<<<dim3(48, 32), 256, 0, stream>>>(Xb, WtQ, Qb, Kb, Vb, fc, fs);
  transpose_v_kernel<<<dim3(32, 2, 32), 256, 0, stream>>>(Vb, Vt);
  flash_kernel<<<dim3(32, 16, 2), 128, 0, stream>>>(Qb, Kb, Vt, O);
  adapter_add_kernel<<<16384, 256, 0, stream>>>(O, Qb, ak, av, gate, Ob);
  // output projection -> d_out fp32
  gemm_kernel<<<dim3(16, 32), 256, 0, stream>>>(Ob, WtO, (float*)d_out, 4096, 2048, 2048);
}

// Round 3
// 570.002 us; speedup vs baseline: 1.0943x; 1.0943x over previous
//
#include <hip/hip_runtime.h>

// ---------------------------------------------------------------------------
// Attention_16698832847178: B=2,S=2048,D=2048,H=16,HD=128,L=10
// R3: flash with (a) per-CU-balanced static qt assignment (every CU's 4
// co-resident blocks sum to 66 k-tile iters), (b) row-sum via ones-column
// MFMA (removes shfl sum chain + lrow), (c) DPP butterflies for row-max.
// ---------------------------------------------------------------------------

typedef unsigned short ushort_t;
typedef unsigned int uint32;
typedef __attribute__((ext_vector_type(8))) short bf16x8;   // 8 bf16 = 4 VGPRs
typedef __attribute__((ext_vector_type(4))) float f32x4;

__device__ __forceinline__ void async16(void* lds, const void* g) {
  __builtin_amdgcn_global_load_lds((const __attribute__((address_space(1))) void*)g,
                                   (__attribute__((address_space(3))) void*)lds,
                                   16, 0, 0);
}
__device__ __forceinline__ ushort_t f2bf(float f) {
  uint32 u = __float_as_uint(f);
  u += 0x7FFFu + ((u >> 16) & 1u);   // round-to-nearest-even
  return (ushort_t)(u >> 16);
}
__device__ __forceinline__ float bf2f(ushort_t b) {
  return __uint_as_float(((uint32)b) << 16);
}
// max with DPP-shuffled partner (patterns within 16 lanes; all lanes active)
#define DPP_MAX(t, ctrl) \
  t = fmaxf(t, __int_as_float(__builtin_amdgcn_update_dpp( \
      0, __float_as_int(t), (ctrl), 0xf, 0xf, true)))
__device__ __forceinline__ float rowmax16(float t) {
  DPP_MAX(t, 0xB1);   // quad_perm [1,0,3,2]  : xor 1
  DPP_MAX(t, 0x4E);   // quad_perm [2,3,0,1]  : xor 2
  t = fmaxf(t, __int_as_float(__builtin_amdgcn_ds_swizzle(
      __float_as_int(t), 0x101F)));                  // xor 4
  DPP_MAX(t, 0x128);  // row_ror:8            : xor 8
  return t;
}

// ---------------------------------------------------------------------------
// cast x (fp32) -> bf16, 8 elements/thread
__global__ __launch_bounds__(256) void cast_x_kernel(const float* __restrict__ x,
                                                     ushort_t* __restrict__ Xb) {
  size_t i = ((size_t)blockIdx.x * 256 + threadIdx.x) * 8;
  float4 a = *(const float4*)(x + i);
  float4 b = *(const float4*)(x + i + 4);
  uint4 o;
  o.x = (uint32)f2bf(a.x) | ((uint32)f2bf(a.y) << 16);
  o.y = (uint32)f2bf(a.z) | ((uint32)f2bf(a.w) << 16);
  o.z = (uint32)f2bf(b.x) | ((uint32)f2bf(b.y) << 16);
  o.w = (uint32)f2bf(b.z) | ((uint32)f2bf(b.w) << 16);
  *(uint4*)(Xb + i) = o;
}

// ---------------------------------------------------------------------------
// W[k][n] fp32 -> Wt[n][k] bf16 (64x64 tiles)
__global__ __launch_bounds__(256) void transpose_w_kernel(
    const float* __restrict__ w0, const float* __restrict__ w1,
    const float* __restrict__ w2, const float* __restrict__ w3,
    ushort_t* __restrict__ outBase) {
  const float* W = (blockIdx.z == 0) ? w0 : (blockIdx.z == 1) ? w1
                 : (blockIdx.z == 2) ? w2 : w3;
  ushort_t* Wt = outBase + (size_t)blockIdx.z * 4194304;  // 2048*2048
  __shared__ float L[64][65];
  int t = threadIdx.x, tc = t & 63, tr = t >> 6;
  int k0 = blockIdx.x * 64, n0 = blockIdx.y * 64;
  for (int i = 0; i < 16; ++i) {
    int r = i * 4 + tr;
    L[r][tc] = W[(size_t)(k0 + r) * 2048 + n0 + tc];
  }
  __syncthreads();
  for (int i = 0; i < 16; ++i) {
    int r = i * 4 + tr;
    Wt[(size_t)(n0 + r) * 2048 + k0 + tc] = f2bf(L[tc][r]);
  }
}

// ---------------------------------------------------------------------------
// Vb (B,S,H,HD) bf16 -> Vt (B,H,HD,S) bf16
__global__ __launch_bounds__(256) void transpose_v_kernel(
    const ushort_t* __restrict__ Vb, ushort_t* __restrict__ Vt) {
  __shared__ ushort_t L[64][65];
  int t = threadIdx.x, tc = t & 63, tr = t >> 6;
  int s0 = blockIdx.x * 64, d0 = blockIdx.y * 64;
  int bh = blockIdx.z, b = bh >> 4, h = bh & 15;
  for (int i = 0; i < 16; ++i) {
    int r = i * 4 + tr;
    L[r][tc] = Vb[((size_t)b * 2048 + s0 + r) * 2048 + h * 128 + d0 + tc];
  }
  __syncthreads();
  for (int i = 0; i < 16; ++i) {
    int r = i * 4 + tr;
    Vt[((size_t)bh * 128 + d0 + r) * 2048 + s0 + tc] = L[tc][r];
  }
}

// ---------------------------------------------------------------------------
// adapter projections: ak/av[l][n] = sum_k adapter[l][k] * W[k][n]  (fp32)
__global__ __launch_bounds__(256) void adapter_kv_kernel(
    const float* __restrict__ adapter, const float* __restrict__ wk,
    const float* __restrict__ wv, float* __restrict__ ak, float* __restrict__ av) {
  const float* W = blockIdx.z ? wv : wk;
  float* out = blockIdx.z ? av : ak;
  __shared__ float As[10][128];
  int t = threadIdx.x;
  int k0 = blockIdx.y * 128;
  for (int i = t; i < 1280; i += 256)
    As[i >> 7][i & 127] = adapter[(size_t)(i >> 7) * 2048 + k0 + (i & 127)];
  __syncthreads();
  int n = blockIdx.x * 256 + t;
  float acc[10];
#pragma unroll
  for (int l = 0; l < 10; ++l) acc[l] = 0.f;
  for (int kk = 0; kk < 128; ++kk) {
    float wv_ = W[(size_t)(k0 + kk) * 2048 + n];
#pragma unroll
    for (int l = 0; l < 10; ++l) acc[l] += As[l][kk] * wv_;
  }
#pragma unroll
  for (int l = 0; l < 10; ++l) atomicAdd(&out[l * 2048 + n], acc[l]);
}

// ---------------------------------------------------------------------------
// Fused QKV GEMM: C[4096, 6144] = Xb[4096,2048] x WtQKV[6144,2048]^T.
__global__ __launch_bounds__(256) void gemm_qkv_kernel(
    const ushort_t* __restrict__ A, const ushort_t* __restrict__ Bt,
    ushort_t* __restrict__ outQ, ushort_t* __restrict__ outK,
    ushort_t* __restrict__ outV,
    const float* __restrict__ fc, const float* __restrict__ fs) {
  __shared__ char ldsA[16384];
  __shared__ char ldsB[16384];
  const int tid = threadIdx.x;
  const int w = tid >> 6, lane = tid & 63, quad = lane >> 4, l15 = lane & 15;
  const int wm = (w >> 1) * 64, wn = (w & 1) * 64;
  const size_t bm0 = (size_t)blockIdx.y * 128, bn0 = (size_t)blockIdx.x * 128;
  const int K = 2048;

  f32x4 zero4 = {0.f, 0.f, 0.f, 0.f};
  f32x4 acc[4][4];
#pragma unroll
  for (int i = 0; i < 4; ++i)
#pragma unroll
    for (int j = 0; j < 4; ++j) acc[i][j] = zero4;

  const int rS = w * 32;
  const int rowOff = lane >> 3;
  const int cph = lane & 7;

  for (int kt = 0; kt < K; kt += 64) {
#pragma unroll
    for (int i = 0; i < 4; ++i) {
      int r0 = rS + i * 8;
      int row = r0 + rowOff;
      int cl = cph ^ (row & 7);
      async16(ldsA + r0 * 128, A + (bm0 + row) * (size_t)K + kt + cl * 8);
      async16(ldsB + r0 * 128, Bt + (bn0 + row) * (size_t)K + kt + cl * 8);
    }
    __syncthreads();
#pragma unroll
    for (int ks = 0; ks < 2; ++ks) {
      bf16x8 af[4], bfv[4];
      int ch = ks * 4 + quad;
#pragma unroll
      for (int tt = 0; tt < 4; ++tt) {
        int ra = wm + tt * 16 + l15;
        af[tt] = *(const bf16x8*)(ldsA + ra * 128 + ((ch ^ (ra & 7)) * 16));
        int rb = wn + tt * 16 + l15;
        bfv[tt] = *(const bf16x8*)(ldsB + rb * 128 + ((ch ^ (rb & 7)) * 16));
      }
#pragma unroll
      for (int i = 0; i < 4; ++i)
#pragma unroll
        for (int j = 0; j < 4; ++j)
          acc[i][j] = __builtin_amdgcn_mfma_f32_16x16x32_bf16(af[i], bfv[j], acc[i][j], 0, 0, 0);
    }
    __syncthreads();
  }

  const int seg = (int)(bn0 >> 11);           // 0=Q, 1=K, 2=V
  ushort_t* ob = (seg == 0) ? outQ : (seg == 1) ? outK : outV;
  const bool rope = (seg < 2);
#pragma unroll
  for (int i = 0; i < 4; ++i)
#pragma unroll
    for (int r = 0; r < 4; ++r) {
      size_t m = bm0 + wm + i * 16 + quad * 4 + r;
      int s = (int)(m & 2047);
#pragma unroll
      for (int j = 0; j < 4; ++j) {
        size_t ngl = bn0 + wn + j * 16 + l15;
        size_t n = ngl & 2047;
        float v = acc[i][j][r];
        if (rope) {
          float v2 = __shfl_xor(v, 1, 64);    // RoPE pair partner (col n^1)
          int fi = ((int)n & 127) >> 1;
          float c = fc[s * 64 + fi], sn = fs[s * 64 + fi];
          v = (lane & 1) ? (v2 * sn + v * c) : (v * c - v2 * sn);
        }
        ob[m * 2048 + n] = f2bf(v);
      }
    }
}

// ---------------------------------------------------------------------------
// Generic GEMM (fp32 out) for the output projection.
__global__ __launch_bounds__(256) void gemm_kernel(
    const ushort_t* __restrict__ A, const ushort_t* __restrict__ Bt,
    float* __restrict__ out, int M, int N, int K) {
  __shared__ char ldsA[16384];
  __shared__ char ldsB[16384];
  const int tid = threadIdx.x;
  const int w = tid >> 6, lane = tid & 63, quad = lane >> 4, l15 = lane & 15;
  const int wm = (w >> 1) * 64, wn = (w & 1) * 64;
  const size_t bm0 = (size_t)blockIdx.y * 128, bn0 = (size_t)blockIdx.x * 128;

  f32x4 zero4 = {0.f, 0.f, 0.f, 0.f};
  f32x4 acc[4][4];
#pragma unroll
  for (int i = 0; i < 4; ++i)
#pragma unroll
    for (int j = 0; j < 4; ++j) acc[i][j] = zero4;

  const int rS = w * 32;
  const int rowOff = lane >> 3;
  const int cph = lane & 7;

  for (int kt = 0; kt < K; kt += 64) {
#pragma unroll
    for (int i = 0; i < 4; ++i) {
      int r0 = rS + i * 8;
      int row = r0 + rowOff;
      int cl = cph ^ (row & 7);
      async16(ldsA + r0 * 128, A + (bm0 + row) * (size_t)K + kt + cl * 8);
      async16(ldsB + r0 * 128, Bt + (bn0 + row) * (size_t)K + kt + cl * 8);
    }
    __syncthreads();
#pragma unroll
    for (int ks = 0; ks < 2; ++ks) {
      bf16x8 af[4], bfv[4];
      int ch = ks * 4 + quad;
#pragma unroll
      for (int tt = 0; tt < 4; ++tt) {
        int ra = wm + tt * 16 + l15;
        af[tt] = *(const bf16x8*)(ldsA + ra * 128 + ((ch ^ (ra & 7)) * 16));
        int rb = wn + tt * 16 + l15;
        bfv[tt] = *(const bf16x8*)(ldsB + rb * 128 + ((ch ^ (rb & 7)) * 16));
      }
#pragma unroll
      for (int i = 0; i < 4; ++i)
#pragma unroll
        for (int j = 0; j < 4; ++j)
          acc[i][j] = __builtin_amdgcn_mfma_f32_16x16x32_bf16(af[i], bfv[j], acc[i][j], 0, 0, 0);
    }
    __syncthreads();
  }
#pragma unroll
  for (int i = 0; i < 4; ++i)
#pragma unroll
    for (int r = 0; r < 4; ++r) {
      size_t m = bm0 + wm + i * 16 + quad * 4 + r;
#pragma unroll
      for (int j = 0; j < 4; ++j) {
        size_t n = bn0 + wn + j * 16 + l15;
        out[m * N + n] = acc[i][j][r];
      }
    }
}

// ---------------------------------------------------------------------------
// Flash attention, causal. 128 threads (2 waves), q-tile 64, k-tile 64.
// LDS 40KB -> 4 blocks/CU. Block index -> (qt,h,b) chosen so each CU's four
// co-resident blocks (i = c, c+256, c+512, c+768 under mod-256 dispatch)
// get qt sets {u, 31-u, (u+8)&31, (23-u)&31}: Sum(qt+1) = 66 for every CU.
// Row-sum via ones-column MFMA (osum); row-max via DPP butterflies.
__global__ __launch_bounds__(128) void flash_kernel(
    const ushort_t* __restrict__ Qb, const ushort_t* __restrict__ Kb,
    const ushort_t* __restrict__ Vt, float* __restrict__ O) {
  __shared__ char ldsK[16384];   // 64 tok x 256B, chunk swz ^(row&15)
  __shared__ char ldsV[16384];   // 128 d x 128B, chunk swz ^(row&7)
  __shared__ char ldsP[8192];    // 64 q x 128B, chunk swz ^(row&7)
  const int tid = threadIdx.x;
  const int w = tid >> 6, lane = tid & 63, quad = lane >> 4, l15 = lane & 15;
  // balanced static assignment
  const int i = blockIdx.x;
  const int p = i >> 8, c = i & 255;
  const int u = c >> 3, v = c & 7;
  const int w0 = (p < 2) ? u : ((u + 8) & 31);
  const int qt = (p & 1) ? (31 - w0) : w0;
  const int hb = (p << 3) | v;
  const int h = hb >> 1, b = hb & 1;
  const float scale = 0.08838834764831845f;  // 1/sqrt(128)

  // ones B-fragment (bf16 1.0) for MFMA row-sum
  bf16x8 ones;
#pragma unroll
  for (int j = 0; j < 8; ++j) ones[j] = (short)0x3F80;

  // Q fragments in registers: 2 m-tiles x 4 d-steps
  bf16x8 qf[2][4];
#pragma unroll
  for (int mt = 0; mt < 2; ++mt) {
    size_t qrow = (size_t)qt * 64 + w * 32 + mt * 16 + l15;
    const ushort_t* base = Qb + ((size_t)b * 2048 + qrow) * 2048 + h * 128 + quad * 8;
#pragma unroll
    for (int ds = 0; ds < 4; ++ds) qf[mt][ds] = *(const bf16x8*)(base + ds * 32);
  }

  f32x4 zero4 = {0.f, 0.f, 0.f, 0.f};
  f32x4 oacc[2][8];
  f32x4 osum[2];
  float mrow[2][4];
#pragma unroll
  for (int mt = 0; mt < 2; ++mt) {
#pragma unroll
    for (int n8 = 0; n8 < 8; ++n8) oacc[mt][n8] = zero4;
    osum[mt] = zero4;
#pragma unroll
    for (int r = 0; r < 4; ++r) mrow[mt][r] = -1e30f;
  }

  for (int kt = 0; kt <= qt; ++kt) {
    // stage K-tile: wave w covers rows w*32..w*32+31 (8 instrs x 4 rows)
#pragma unroll
    for (int ii = 0; ii < 8; ++ii) {
      int r0 = w * 32 + ii * 4;
      int row = r0 + (lane >> 4);
      int cl = (lane & 15) ^ (row & 15);
      async16(ldsK + r0 * 256,
              Kb + ((size_t)b * 2048 + kt * 64 + row) * 2048 + h * 128 + cl * 8);
    }
    // stage V^T-tile: wave w covers d-rows w*64..w*64+63 (8 instrs x 8 rows)
#pragma unroll
    for (int ii = 0; ii < 8; ++ii) {
      int d0 = w * 64 + ii * 8;
      int dr = d0 + (lane >> 3);
      int cl = (lane & 7) ^ (dr & 7);
      async16(ldsV + d0 * 128,
              Vt + ((size_t)(b * 16 + h) * 128 + dr) * 2048 + kt * 64 + cl * 8);
    }
    __syncthreads();

    // S = Q K^T
    f32x4 sacc[2][4];
#pragma unroll
    for (int mt = 0; mt < 2; ++mt)
#pragma unroll
      for (int nt = 0; nt < 4; ++nt) sacc[mt][nt] = zero4;
#pragma unroll
    for (int ds = 0; ds < 4; ++ds) {
      bf16x8 kf[4];
      int ch = ds * 4 + quad;
#pragma unroll
      for (int nt = 0; nt < 4; ++nt) {
        int row = nt * 16 + l15;
        kf[nt] = *(const bf16x8*)(ldsK + row * 256 + ((ch ^ (row & 15)) * 16));
      }
#pragma unroll
      for (int mt = 0; mt < 2; ++mt)
#pragma unroll
        for (int nt = 0; nt < 4; ++nt)
          sacc[mt][nt] = __builtin_amdgcn_mfma_f32_16x16x32_bf16(qf[mt][ds], kf[nt], sacc[mt][nt], 0, 0, 0);
    }

    // online softmax (max via DPP butterflies; sum via ones-MFMA later)
    const bool domask = (kt == qt);
#pragma unroll
    for (int mt = 0; mt < 2; ++mt) {
      float tmax[4] = {-1e30f, -1e30f, -1e30f, -1e30f};
      const int qbase = qt * 64 + w * 32 + mt * 16 + quad * 4;
#pragma unroll
      for (int nt = 0; nt < 4; ++nt) {
        int kg = kt * 64 + nt * 16 + l15;
#pragma unroll
        for (int r = 0; r < 4; ++r) {
          float s = sacc[mt][nt][r] * scale;
          if (domask && kg > qbase + r) s = -1e30f;
          sacc[mt][nt][r] = s;
          tmax[r] = fmaxf(tmax[r], s);
        }
      }
#pragma unroll
      for (int r = 0; r < 4; ++r) {
        float t = rowmax16(tmax[r]);
        float mnew = fmaxf(mrow[mt][r], t);
        float alpha = __expf(mrow[mt][r] - mnew);
        mrow[mt][r] = mnew;
        osum[mt][r] *= alpha;
#pragma unroll
        for (int n8 = 0; n8 < 8; ++n8) oacc[mt][n8][r] *= alpha;
        tmax[r] = mnew;
      }
      // P (C-layout) -> LDS (A-layout readable), bf16; per-wave private rows
#pragma unroll
      for (int nt = 0; nt < 4; ++nt) {
        int col = nt * 16 + l15;
#pragma unroll
        for (int r = 0; r < 4; ++r) {
          float pv = __expf(sacc[mt][nt][r] - tmax[r]);
          int prow = w * 32 + mt * 16 + quad * 4 + r;
          int addr = prow * 128 + (((col >> 3) ^ (prow & 7)) * 16) + (col & 7) * 2;
          *(ushort_t*)(ldsP + addr) = f2bf(pv);
        }
      }
    }

    // O += P V ; osum += P 1
#pragma unroll
    for (int ks = 0; ks < 2; ++ks) {
      int ch = ks * 4 + quad;
      bf16x8 pf[2];
#pragma unroll
      for (int mt = 0; mt < 2; ++mt) {
        int prow = w * 32 + mt * 16 + l15;
        pf[mt] = *(const bf16x8*)(ldsP + prow * 128 + ((ch ^ (prow & 7)) * 16));
      }
#pragma unroll
      for (int mt = 0; mt < 2; ++mt)
        osum[mt] = __builtin_amdgcn_mfma_f32_16x16x32_bf16(pf[mt], ones, osum[mt], 0, 0, 0);
#pragma unroll
      for (int n8 = 0; n8 < 8; ++n8) {
        int dr = n8 * 16 + l15;
        bf16x8 vf = *(const bf16x8*)(ldsV + dr * 128 + ((ch ^ (dr & 7)) * 16));
#pragma unroll
        for (int mt = 0; mt < 2; ++mt)
          oacc[mt][n8] = __builtin_amdgcn_mfma_f32_16x16x32_bf16(pf[mt], vf, oacc[mt][n8], 0, 0, 0);
      }
    }
    __syncthreads();
  }

  // normalize + store O (B,S,H,HD) fp32 (osum holds row sums in every lane)
#pragma unroll
  for (int mt = 0; mt < 2; ++mt) {
    float rl[4];
#pragma unroll
    for (int r = 0; r < 4; ++r) rl[r] = 1.f / osum[mt][r];
    size_t qb0 = (size_t)qt * 64 + w * 32 + mt * 16 + quad * 4;
#pragma unroll
    for (int n8 = 0; n8 < 8; ++n8) {
      size_t col = (size_t)h * 128 + n8 * 16 + l15;
#pragma unroll
      for (int r = 0; r < 4; ++r)
        O[((size_t)b * 2048 + qb0 + r) * 2048 + col] = oacc[mt][n8][r] * rl[r];
    }
  }
}

// ---------------------------------------------------------------------------
// adapter attention add + cast O fp32 -> bf16. One wave per (b,s,h).
__global__ __launch_bounds__(256) void adapter_add_kernel(
    const float* __restrict__ O, const ushort_t* __restrict__ Qb,
    const float* __restrict__ ak, const float* __restrict__ av,
    const float* __restrict__ gate, ushort_t* __restrict__ Ob) {
  const int w = threadIdx.x >> 6, lane = threadIdx.x & 63;
  const size_t idx = (size_t)blockIdx.x * 4 + w;   // (b*2048+s)*16 + h
  const int h = (int)(idx & 15);
  const size_t bs = idx >> 4;
  const size_t base = bs * 2048 + h * 128 + lane * 2;
  uint32 qraw = *(const uint32*)(Qb + base);
  float q0 = bf2f((ushort_t)(qraw & 0xFFFFu));
  float q1 = bf2f((ushort_t)(qraw >> 16));
  const float scale = 0.08838834764831845f;
  const int col = h * 128 + lane * 2;
  float sc[10];
#pragma unroll
  for (int l = 0; l < 10; ++l) {
    float2 a = *(const float2*)(ak + l * 2048 + col);
    float v = q0 * a.x + q1 * a.y;
    v += __shfl_xor(v, 32, 64);
    v += __shfl_xor(v, 16, 64);
    v += __shfl_xor(v, 8, 64);
    v += __shfl_xor(v, 4, 64);
    v += __shfl_xor(v, 2, 64);
    v += __shfl_xor(v, 1, 64);
    sc[l] = v * scale;
  }
  float mx = sc[0];
#pragma unroll
  for (int l = 1; l < 10; ++l) mx = fmaxf(mx, sc[l]);
  float e[10], sum = 0.f;
#pragma unroll
  for (int l = 0; l < 10; ++l) { e[l] = __expf(sc[l] - mx); sum += e[l]; }
  float g = gate[h] / sum;
  float o0 = 0.f, o1 = 0.f;
#pragma unroll
  for (int l = 0; l < 10; ++l) {
    float2 a = *(const float2*)(av + l * 2048 + col);
    o0 += e[l] * a.x;
    o1 += e[l] * a.y;
  }
  float r0 = O[base] + g * o0;
  float r1 = O[base + 1] + g * o1;
  *(uint32*)(Ob + base) = (uint32)f2bf(r0) | ((uint32)f2bf(r1) << 16);
}

// ---------------------------------------------------------------------------
extern "C" void kernel_launch(void* const* d_in, const int* in_sizes, int n_in,
                              void* d_out, int out_size, void* d_ws, size_t ws_size,
                              hipStream_t stream) {
  (void)in_sizes; (void)n_in; (void)out_size; (void)ws_size;
  const float* x       = (const float*)d_in[0];
  const float* wq      = (const float*)d_in[1];
  const float* wk      = (const float*)d_in[2];
  const float* wv      = (const float*)d_in[3];
  const float* wo      = (const float*)d_in[4];
  const float* adapter = (const float*)d_in[5];
  const float* gate    = (const float*)d_in[6];
  const float* fc      = (const float*)d_in[7];
  const float* fs      = (const float*)d_in[8];

  char* ws = (char*)d_ws;
  ushort_t* Xb  = (ushort_t*)(ws + 0);            // 16,777,216  (reused as Ob)
  ushort_t* WtQ = (ushort_t*)(ws + 16777216);     // 8,388,608 x4 contiguous
  ushort_t* WtO = (ushort_t*)(ws + 41943040);
  ushort_t* Qb  = (ushort_t*)(ws + 50331648);
  ushort_t* Kb  = (ushort_t*)(ws + 67108864);
  ushort_t* Vt  = (ushort_t*)(ws + 83886080);
  float*    O   = (float*)   (ws + 100663296);
  ushort_t* Vb  = (ushort_t*)(ws + 100663296);    // temp (first half of O region)
  float*    ak  = (float*)   (ws + 134217728);
  float*    av  = (float*)   (ws + 134299648);
  ushort_t* Ob  = Xb;

  cast_x_kernel<<<4096, 256, 0, stream>>>(x, Xb);
  transpose_w_kernel<<<dim3(32, 32, 4), 256, 0, stream>>>(wq, wk, wv, wo, WtQ);
  hipMemsetAsync(ak, 0, 163840, stream);
  adapter_kv_kernel<<<dim3(8, 16, 2), 256, 0, stream>>>(adapter, wk, wv, ak, av);
  gemm_qkv_kernel<<<dim3(48, 32), 256, 0, stream>>>(Xb, WtQ, Qb, Kb, Vb, fc, fs);
  transpose_v_kernel<<<dim3(32, 2, 32), 256, 0, stream>>>(Vb, Vt);
  flash_kernel<<<1024, 128, 0, stream>>>(Qb, Kb, Vt, O);
  adapter_add_kernel<<<16384, 256, 0, stream>>>(O, Qb, ak, av, gate, Ob);
  gemm_kernel<<<dim3(16, 32), 256, 0, stream>>>(Ob, WtO, (float*)d_out, 4096, 2048, 2048);
}

// Round 4
// 535.238 us; speedup vs baseline: 1.1654x; 1.0650x over previous
//
#include <hip/hip_runtime.h>

// ---------------------------------------------------------------------------
// Attention_16698832847178: B=2,S=2048,D=2048,H=16,HD=128,L=10
// R4: flash q-tile 128 / 256 threads (halves block-iters per CU: 66 -> 34,
// balanced {u,15-u} qt pairs per CU); GEMM epilogues use packed rope table +
// DPP pairing + dword stores; transpose_w dword stores.
// ---------------------------------------------------------------------------

typedef unsigned short ushort_t;
typedef unsigned int uint32;
typedef __attribute__((ext_vector_type(8))) short bf16x8;   // 8 bf16 = 4 VGPRs
typedef __attribute__((ext_vector_type(4))) float f32x4;

__device__ __forceinline__ void async16(void* lds, const void* g) {
  __builtin_amdgcn_global_load_lds((const __attribute__((address_space(1))) void*)g,
                                   (__attribute__((address_space(3))) void*)lds,
                                   16, 0, 0);
}
__device__ __forceinline__ ushort_t f2bf(float f) {
  uint32 u = __float_as_uint(f);
  u += 0x7FFFu + ((u >> 16) & 1u);   // round-to-nearest-even
  return (ushort_t)(u >> 16);
}
__device__ __forceinline__ float bf2f(ushort_t b) {
  return __uint_as_float(((uint32)b) << 16);
}
// value from lane^1 via DPP quad_perm [1,0,3,2] (VALU, no LDS)
__device__ __forceinline__ float dpp_xor1(float v) {
  return __int_as_float(__builtin_amdgcn_update_dpp(
      0, __float_as_int(v), 0xB1, 0xf, 0xf, true));
}
#define DPP_MAX(t, ctrl) \
  t = fmaxf(t, __int_as_float(__builtin_amdgcn_update_dpp( \
      0, __float_as_int(t), (ctrl), 0xf, 0xf, true)))
__device__ __forceinline__ float rowmax16(float t) {
  DPP_MAX(t, 0xB1);   // quad_perm [1,0,3,2]  : xor 1
  DPP_MAX(t, 0x4E);   // quad_perm [2,3,0,1]  : xor 2
  t = fmaxf(t, __int_as_float(__builtin_amdgcn_ds_swizzle(
      __float_as_int(t), 0x101F)));                  // xor 4
  DPP_MAX(t, 0x128);  // row_ror:8            : xor 8
  return t;
}

// ---------------------------------------------------------------------------
// cast x (fp32) -> bf16, 8 elements/thread
__global__ __launch_bounds__(256) void cast_x_kernel(const float* __restrict__ x,
                                                     ushort_t* __restrict__ Xb) {
  size_t i = ((size_t)blockIdx.x * 256 + threadIdx.x) * 8;
  float4 a = *(const float4*)(x + i);
  float4 b = *(const float4*)(x + i + 4);
  uint4 o;
  o.x = (uint32)f2bf(a.x) | ((uint32)f2bf(a.y) << 16);
  o.y = (uint32)f2bf(a.z) | ((uint32)f2bf(a.w) << 16);
  o.z = (uint32)f2bf(b.x) | ((uint32)f2bf(b.y) << 16);
  o.w = (uint32)f2bf(b.z) | ((uint32)f2bf(b.w) << 16);
  *(uint4*)(Xb + i) = o;
}

// ---------------------------------------------------------------------------
// pack rope table: fcs[s][fi] = (cos, sin)
__global__ __launch_bounds__(256) void rope_pack_kernel(
    const float* __restrict__ fc, const float* __restrict__ fs,
    float2* __restrict__ fcs) {
  int i = blockIdx.x * 256 + threadIdx.x;   // < 131072
  fcs[i] = make_float2(fc[i], fs[i]);
}

// ---------------------------------------------------------------------------
// W[k][n] fp32 -> Wt[n][k] bf16 (64x64 tiles), dword stores
__global__ __launch_bounds__(256) void transpose_w_kernel(
    const float* __restrict__ w0, const float* __restrict__ w1,
    const float* __restrict__ w2, const float* __restrict__ w3,
    ushort_t* __restrict__ outBase) {
  const float* W = (blockIdx.z == 0) ? w0 : (blockIdx.z == 1) ? w1
                 : (blockIdx.z == 2) ? w2 : w3;
  ushort_t* Wt = outBase + (size_t)blockIdx.z * 4194304;  // 2048*2048
  __shared__ float L[64][65];
  int t = threadIdx.x, tc = t & 63, tr = t >> 6;
  int k0 = blockIdx.x * 64, n0 = blockIdx.y * 64;
  for (int i = 0; i < 16; ++i) {
    int r = i * 4 + tr;
    L[r][tc] = W[(size_t)(k0 + r) * 2048 + n0 + tc];
  }
  __syncthreads();
  int tr8 = t >> 5, tc2 = t & 31;
  for (int i = 0; i < 8; ++i) {
    int r = i * 8 + tr8;
    uint32 pk = (uint32)f2bf(L[2 * tc2][r]) | ((uint32)f2bf(L[2 * tc2 + 1][r]) << 16);
    *(uint32*)(Wt + (size_t)(n0 + r) * 2048 + k0 + 2 * tc2) = pk;
  }
}

// ---------------------------------------------------------------------------
// Vb (B,S,H,HD) bf16 -> Vt (B,H,HD,S) bf16
__global__ __launch_bounds__(256) void transpose_v_kernel(
    const ushort_t* __restrict__ Vb, ushort_t* __restrict__ Vt) {
  __shared__ ushort_t L[64][65];
  int t = threadIdx.x, tc = t & 63, tr = t >> 6;
  int s0 = blockIdx.x * 64, d0 = blockIdx.y * 64;
  int bh = blockIdx.z, b = bh >> 4, h = bh & 15;
  for (int i = 0; i < 16; ++i) {
    int r = i * 4 + tr;
    L[r][tc] = Vb[((size_t)b * 2048 + s0 + r) * 2048 + h * 128 + d0 + tc];
  }
  __syncthreads();
  for (int i = 0; i < 16; ++i) {
    int r = i * 4 + tr;
    Vt[((size_t)bh * 128 + d0 + r) * 2048 + s0 + tc] = L[tc][r];
  }
}

// ---------------------------------------------------------------------------
// adapter projections: ak/av[l][n] = sum_k adapter[l][k] * W[k][n]  (fp32)
__global__ __launch_bounds__(256) void adapter_kv_kernel(
    const float* __restrict__ adapter, const float* __restrict__ wk,
    const float* __restrict__ wv, float* __restrict__ ak, float* __restrict__ av) {
  const float* W = blockIdx.z ? wv : wk;
  float* out = blockIdx.z ? av : ak;
  __shared__ float As[10][128];
  int t = threadIdx.x;
  int k0 = blockIdx.y * 128;
  for (int i = t; i < 1280; i += 256)
    As[i >> 7][i & 127] = adapter[(size_t)(i >> 7) * 2048 + k0 + (i & 127)];
  __syncthreads();
  int n = blockIdx.x * 256 + t;
  float acc[10];
#pragma unroll
  for (int l = 0; l < 10; ++l) acc[l] = 0.f;
  for (int kk = 0; kk < 128; ++kk) {
    float wv_ = W[(size_t)(k0 + kk) * 2048 + n];
#pragma unroll
    for (int l = 0; l < 10; ++l) acc[l] += As[l][kk] * wv_;
  }
#pragma unroll
  for (int l = 0; l < 10; ++l) atomicAdd(&out[l * 2048 + n], acc[l]);
}

// ---------------------------------------------------------------------------
// Fused QKV GEMM: C[4096, 6144] = Xb[4096,2048] x WtQKV[6144,2048]^T.
__global__ __launch_bounds__(256) void gemm_qkv_kernel(
    const ushort_t* __restrict__ A, const ushort_t* __restrict__ Bt,
    ushort_t* __restrict__ outQ, ushort_t* __restrict__ outK,
    ushort_t* __restrict__ outV,
    const float2* __restrict__ fcs) {
  __shared__ char ldsA[16384];
  __shared__ char ldsB[16384];
  const int tid = threadIdx.x;
  const int w = tid >> 6, lane = tid & 63, quad = lane >> 4, l15 = lane & 15;
  const int wm = (w >> 1) * 64, wn = (w & 1) * 64;
  const size_t bm0 = (size_t)blockIdx.y * 128, bn0 = (size_t)blockIdx.x * 128;
  const int K = 2048;

  f32x4 zero4 = {0.f, 0.f, 0.f, 0.f};
  f32x4 acc[4][4];
#pragma unroll
  for (int i = 0; i < 4; ++i)
#pragma unroll
    for (int j = 0; j < 4; ++j) acc[i][j] = zero4;

  const int rS = w * 32;
  const int rowOff = lane >> 3;
  const int cph = lane & 7;

  for (int kt = 0; kt < K; kt += 64) {
#pragma unroll
    for (int i = 0; i < 4; ++i) {
      int r0 = rS + i * 8;
      int row = r0 + rowOff;
      int cl = cph ^ (row & 7);
      async16(ldsA + r0 * 128, A + (bm0 + row) * (size_t)K + kt + cl * 8);
      async16(ldsB + r0 * 128, Bt + (bn0 + row) * (size_t)K + kt + cl * 8);
    }
    __syncthreads();
#pragma unroll
    for (int ks = 0; ks < 2; ++ks) {
      bf16x8 af[4], bfv[4];
      int ch = ks * 4 + quad;
#pragma unroll
      for (int tt = 0; tt < 4; ++tt) {
        int ra = wm + tt * 16 + l15;
        af[tt] = *(const bf16x8*)(ldsA + ra * 128 + ((ch ^ (ra & 7)) * 16));
        int rb = wn + tt * 16 + l15;
        bfv[tt] = *(const bf16x8*)(ldsB + rb * 128 + ((ch ^ (rb & 7)) * 16));
      }
#pragma unroll
      for (int i = 0; i < 4; ++i)
#pragma unroll
        for (int j = 0; j < 4; ++j)
          acc[i][j] = __builtin_amdgcn_mfma_f32_16x16x32_bf16(af[i], bfv[j], acc[i][j], 0, 0, 0);
    }
    __syncthreads();
  }

  const int seg = (int)(bn0 >> 11);           // 0=Q, 1=K, 2=V
  ushort_t* ob = (seg == 0) ? outQ : (seg == 1) ? outK : outV;
  const bool rope = (seg < 2);
  const bool evenlane = ((lane & 1) == 0);
#pragma unroll
  for (int i = 0; i < 4; ++i)
#pragma unroll
    for (int r = 0; r < 4; ++r) {
      size_t m = bm0 + wm + i * 16 + quad * 4 + r;
      int s = (int)(m & 2047);
#pragma unroll
      for (int j = 0; j < 4; ++j) {
        size_t ngl = bn0 + wn + j * 16 + l15;
        size_t n = ngl & 2047;
        float v = acc[i][j][r];
        if (rope) {
          float v2 = dpp_xor1(v);             // RoPE pair partner (col n^1)
          int fi = ((int)n & 127) >> 1;
          float2 cs = fcs[s * 64 + fi];
          v = (lane & 1) ? (v2 * cs.y + v * cs.x) : (v * cs.x - v2 * cs.y);
        }
        float vo = dpp_xor1(v);               // partner's output value
        if (evenlane) {
          uint32 pk = (uint32)f2bf(v) | ((uint32)f2bf(vo) << 16);
          *(uint32*)(ob + m * 2048 + n) = pk;
        }
      }
    }
}

// ---------------------------------------------------------------------------
// Generic GEMM (fp32 out) for the output projection.
__global__ __launch_bounds__(256) void gemm_kernel(
    const ushort_t* __restrict__ A, const ushort_t* __restrict__ Bt,
    float* __restrict__ out, int M, int N, int K) {
  __shared__ char ldsA[16384];
  __shared__ char ldsB[16384];
  const int tid = threadIdx.x;
  const int w = tid >> 6, lane = tid & 63, quad = lane >> 4, l15 = lane & 15;
  const int wm = (w >> 1) * 64, wn = (w & 1) * 64;
  const size_t bm0 = (size_t)blockIdx.y * 128, bn0 = (size_t)blockIdx.x * 128;

  f32x4 zero4 = {0.f, 0.f, 0.f, 0.f};
  f32x4 acc[4][4];
#pragma unroll
  for (int i = 0; i < 4; ++i)
#pragma unroll
    for (int j = 0; j < 4; ++j) acc[i][j] = zero4;

  const int rS = w * 32;
  const int rowOff = lane >> 3;
  const int cph = lane & 7;

  for (int kt = 0; kt < K; kt += 64) {
#pragma unroll
    for (int i = 0; i < 4; ++i) {
      int r0 = rS + i * 8;
      int row = r0 + rowOff;
      int cl = cph ^ (row & 7);
      async16(ldsA + r0 * 128, A + (bm0 + row) * (size_t)K + kt + cl * 8);
      async16(ldsB + r0 * 128, Bt + (bn0 + row) * (size_t)K + kt + cl * 8);
    }
    __syncthreads();
#pragma unroll
    for (int ks = 0; ks < 2; ++ks) {
      bf16x8 af[4], bfv[4];
      int ch = ks * 4 + quad;
#pragma unroll
      for (int tt = 0; tt < 4; ++tt) {
        int ra = wm + tt * 16 + l15;
        af[tt] = *(const bf16x8*)(ldsA + ra * 128 + ((ch ^ (ra & 7)) * 16));
        int rb = wn + tt * 16 + l15;
        bfv[tt] = *(const bf16x8*)(ldsB + rb * 128 + ((ch ^ (rb & 7)) * 16));
      }
#pragma unroll
      for (int i = 0; i < 4; ++i)
#pragma unroll
        for (int j = 0; j < 4; ++j)
          acc[i][j] = __builtin_amdgcn_mfma_f32_16x16x32_bf16(af[i], bfv[j], acc[i][j], 0, 0, 0);
    }
    __syncthreads();
  }
#pragma unroll
  for (int i = 0; i < 4; ++i)
#pragma unroll
    for (int r = 0; r < 4; ++r) {
      size_t m = bm0 + wm + i * 16 + quad * 4 + r;
#pragma unroll
      for (int j = 0; j < 4; ++j) {
        size_t n = bn0 + wn + j * 16 + l15;
        out[m * N + n] = acc[i][j][r];
      }
    }
}

// ---------------------------------------------------------------------------
// Flash attention, causal. 256 threads (4 waves), q-tile 128 (wave: 32 rows),
// k-tile 64. LDS = 16K (K) + 16K (V^T) + 16K (P) = 48KB.
// Balanced static qt: CU c gets blocks {c, c+256} with qt {u, 15-u} ->
// (2u+2)+(2(15-u)+2) = 34 block-iters on every CU.
__global__ __launch_bounds__(256) void flash_kernel(
    const ushort_t* __restrict__ Qb, const ushort_t* __restrict__ Kb,
    const ushort_t* __restrict__ Vt, float* __restrict__ O) {
  __shared__ char ldsK[16384];   // 64 tok x 256B, chunk swz ^(row&15)
  __shared__ char ldsV[16384];   // 128 d x 128B, chunk swz ^(dr&7)
  __shared__ char ldsP[16384];   // 128 q x 128B, chunk swz ^(prow&7)
  const int tid = threadIdx.x;
  const int w = tid >> 6, lane = tid & 63, quad = lane >> 4, l15 = lane & 15;
  // balanced static assignment over 512 blocks
  const int idx = blockIdx.x;
  const int p = idx >> 8, c = idx & 255;
  const int u = c >> 4, vv = c & 15;
  const int qt = p ? (15 - u) : u;
  const int hb = (p << 4) | vv;
  const int h = hb >> 1, b = hb & 1;
  const float scale = 0.08838834764831845f;  // 1/sqrt(128)

  // ones B-fragment (bf16 1.0) for MFMA row-sum
  bf16x8 ones;
#pragma unroll
  for (int j = 0; j < 8; ++j) ones[j] = (short)0x3F80;

  // Q fragments in registers: 2 m-tiles x 4 d-steps (wave rows w*32..+31)
  bf16x8 qf[2][4];
#pragma unroll
  for (int mt = 0; mt < 2; ++mt) {
    size_t qrow = (size_t)qt * 128 + w * 32 + mt * 16 + l15;
    const ushort_t* base = Qb + ((size_t)b * 2048 + qrow) * 2048 + h * 128 + quad * 8;
#pragma unroll
    for (int ds = 0; ds < 4; ++ds) qf[mt][ds] = *(const bf16x8*)(base + ds * 32);
  }

  f32x4 zero4 = {0.f, 0.f, 0.f, 0.f};
  f32x4 oacc[2][8];
  f32x4 osum[2];
  float mrow[2][4];
#pragma unroll
  for (int mt = 0; mt < 2; ++mt) {
#pragma unroll
    for (int n8 = 0; n8 < 8; ++n8) oacc[mt][n8] = zero4;
    osum[mt] = zero4;
#pragma unroll
    for (int r = 0; r < 4; ++r) mrow[mt][r] = -1e30f;
  }

  const int ktmax = 2 * qt + 1;
  for (int kt = 0; kt <= ktmax; ++kt) {
    // stage K-tile: wave w rows w*16..+15 (4 instrs x 4 rows)
#pragma unroll
    for (int ii = 0; ii < 4; ++ii) {
      int r0 = w * 16 + ii * 4;
      int row = r0 + (lane >> 4);
      int cl = (lane & 15) ^ (row & 15);
      async16(ldsK + r0 * 256,
              Kb + ((size_t)b * 2048 + kt * 64 + row) * 2048 + h * 128 + cl * 8);
    }
    // stage V^T-tile: wave w d-rows w*32..+31 (4 instrs x 8 rows)
#pragma unroll
    for (int ii = 0; ii < 4; ++ii) {
      int d0 = w * 32 + ii * 8;
      int dr = d0 + (lane >> 3);
      int cl = (lane & 7) ^ (dr & 7);
      async16(ldsV + d0 * 128,
              Vt + ((size_t)(b * 16 + h) * 128 + dr) * 2048 + kt * 64 + cl * 8);
    }
    __syncthreads();

    // S = Q K^T
    f32x4 sacc[2][4];
#pragma unroll
    for (int mt = 0; mt < 2; ++mt)
#pragma unroll
      for (int nt = 0; nt < 4; ++nt) sacc[mt][nt] = zero4;
#pragma unroll
    for (int ds = 0; ds < 4; ++ds) {
      bf16x8 kf[4];
      int ch = ds * 4 + quad;
#pragma unroll
      for (int nt = 0; nt < 4; ++nt) {
        int row = nt * 16 + l15;
        kf[nt] = *(const bf16x8*)(ldsK + row * 256 + ((ch ^ (row & 15)) * 16));
      }
#pragma unroll
      for (int mt = 0; mt < 2; ++mt)
#pragma unroll
        for (int nt = 0; nt < 4; ++nt)
          sacc[mt][nt] = __builtin_amdgcn_mfma_f32_16x16x32_bf16(qf[mt][ds], kf[nt], sacc[mt][nt], 0, 0, 0);
    }

    // online softmax (max via DPP butterflies; sum via ones-MFMA)
    const bool domask = (kt >= 2 * qt);
#pragma unroll
    for (int mt = 0; mt < 2; ++mt) {
      float tmax[4] = {-1e30f, -1e30f, -1e30f, -1e30f};
      const int qbase = qt * 128 + w * 32 + mt * 16 + quad * 4;
#pragma unroll
      for (int nt = 0; nt < 4; ++nt) {
        int kg = kt * 64 + nt * 16 + l15;
#pragma unroll
        for (int r = 0; r < 4; ++r) {
          float s = sacc[mt][nt][r] * scale;
          if (domask && kg > qbase + r) s = -1e30f;
          sacc[mt][nt][r] = s;
          tmax[r] = fmaxf(tmax[r], s);
        }
      }
#pragma unroll
      for (int r = 0; r < 4; ++r) {
        float t = rowmax16(tmax[r]);
        float mnew = fmaxf(mrow[mt][r], t);
        float alpha = __expf(mrow[mt][r] - mnew);
        mrow[mt][r] = mnew;
        osum[mt][r] *= alpha;
#pragma unroll
        for (int n8 = 0; n8 < 8; ++n8) oacc[mt][n8][r] *= alpha;
        tmax[r] = mnew;
      }
      // P (C-layout) -> LDS (A-layout readable), bf16; per-wave private rows
#pragma unroll
      for (int nt = 0; nt < 4; ++nt) {
        int col = nt * 16 + l15;
#pragma unroll
        for (int r = 0; r < 4; ++r) {
          float pv = __expf(sacc[mt][nt][r] - tmax[r]);
          int prow = w * 32 + mt * 16 + quad * 4 + r;
          int addr = prow * 128 + (((col >> 3) ^ (prow & 7)) * 16) + (col & 7) * 2;
          *(ushort_t*)(ldsP + addr) = f2bf(pv);
        }
      }
    }

    // O += P V ; osum += P 1
#pragma unroll
    for (int ks = 0; ks < 2; ++ks) {
      int ch = ks * 4 + quad;
      bf16x8 pf[2];
#pragma unroll
      for (int mt = 0; mt < 2; ++mt) {
        int prow = w * 32 + mt * 16 + l15;
        pf[mt] = *(const bf16x8*)(ldsP + prow * 128 + ((ch ^ (prow & 7)) * 16));
      }
#pragma unroll
      for (int mt = 0; mt < 2; ++mt)
        osum[mt] = __builtin_amdgcn_mfma_f32_16x16x32_bf16(pf[mt], ones, osum[mt], 0, 0, 0);
#pragma unroll
      for (int n8 = 0; n8 < 8; ++n8) {
        int dr = n8 * 16 + l15;
        bf16x8 vf = *(const bf16x8*)(ldsV + dr * 128 + ((ch ^ (dr & 7)) * 16));
#pragma unroll
        for (int mt = 0; mt < 2; ++mt)
          oacc[mt][n8] = __builtin_amdgcn_mfma_f32_16x16x32_bf16(pf[mt], vf, oacc[mt][n8], 0, 0, 0);
      }
    }
    __syncthreads();
  }

  // normalize + store O (B,S,H,HD) fp32 (osum holds row sums in every lane)
#pragma unroll
  for (int mt = 0; mt < 2; ++mt) {
    float rl[4];
#pragma unroll
    for (int r = 0; r < 4; ++r) rl[r] = 1.f / osum[mt][r];
    size_t qb0 = (size_t)qt * 128 + w * 32 + mt * 16 + quad * 4;
#pragma unroll
    for (int n8 = 0; n8 < 8; ++n8) {
      size_t col = (size_t)h * 128 + n8 * 16 + l15;
#pragma unroll
      for (int r = 0; r < 4; ++r)
        O[((size_t)b * 2048 + qb0 + r) * 2048 + col] = oacc[mt][n8][r] * rl[r];
    }
  }
}

// ---------------------------------------------------------------------------
// adapter attention add + cast O fp32 -> bf16. One wave per (b,s,h).
__global__ __launch_bounds__(256) void adapter_add_kernel(
    const float* __restrict__ O, const ushort_t* __restrict__ Qb,
    const float* __restrict__ ak, const float* __restrict__ av,
    const float* __restrict__ gate, ushort_t* __restrict__ Ob) {
  const int w = threadIdx.x >> 6, lane = threadIdx.x & 63;
  const size_t idx = (size_t)blockIdx.x * 4 + w;   // (b*2048+s)*16 + h
  const int h = (int)(idx & 15);
  const size_t bs = idx >> 4;
  const size_t base = bs * 2048 + h * 128 + lane * 2;
  uint32 qraw = *(const uint32*)(Qb + base);
  float q0 = bf2f((ushort_t)(qraw & 0xFFFFu));
  float q1 = bf2f((ushort_t)(qraw >> 16));
  const float scale = 0.08838834764831845f;
  const int col = h * 128 + lane * 2;
  float sc[10];
#pragma unroll
  for (int l = 0; l < 10; ++l) {
    float2 a = *(const float2*)(ak + l * 2048 + col);
    float v = q0 * a.x + q1 * a.y;
    v += __shfl_xor(v, 32, 64);
    v += __shfl_xor(v, 16, 64);
    v += __shfl_xor(v, 8, 64);
    v += __shfl_xor(v, 4, 64);
    v += __shfl_xor(v, 2, 64);
    v += __shfl_xor(v, 1, 64);
    sc[l] = v * scale;
  }
  float mx = sc[0];
#pragma unroll
  for (int l = 1; l < 10; ++l) mx = fmaxf(mx, sc[l]);
  float e[10], sum = 0.f;
#pragma unroll
  for (int l = 0; l < 10; ++l) { e[l] = __expf(sc[l] - mx); sum += e[l]; }
  float g = gate[h] / sum;
  float o0 = 0.f, o1 = 0.f;
#pragma unroll
  for (int l = 0; l < 10; ++l) {
    float2 a = *(const float2*)(av + l * 2048 + col);
    o0 += e[l] * a.x;
    o1 += e[l] * a.y;
  }
  float r0 = O[base] + g * o0;
  float r1 = O[base + 1] + g * o1;
  *(uint32*)(Ob + base) = (uint32)f2bf(r0) | ((uint32)f2bf(r1) << 16);
}

// ---------------------------------------------------------------------------
extern "C" void kernel_launch(void* const* d_in, const int* in_sizes, int n_in,
                              void* d_out, int out_size, void* d_ws, size_t ws_size,
                              hipStream_t stream) {
  (void)in_sizes; (void)n_in; (void)out_size; (void)ws_size;
  const float* x       = (const float*)d_in[0];
  const float* wq      = (const float*)d_in[1];
  const float* wk      = (const float*)d_in[2];
  const float* wv      = (const float*)d_in[3];
  const float* wo      = (const float*)d_in[4];
  const float* adapter = (const float*)d_in[5];
  const float* gate    = (const float*)d_in[6];
  const float* fc      = (const float*)d_in[7];
  const float* fs      = (const float*)d_in[8];

  char* ws = (char*)d_ws;
  ushort_t* Xb  = (ushort_t*)(ws + 0);            // 16 MB (reused as Ob)
  ushort_t* WtQ = (ushort_t*)(ws + 16777216);     // 8 MB x4 contiguous
  ushort_t* WtO = (ushort_t*)(ws + 41943040);
  ushort_t* Qb  = (ushort_t*)(ws + 50331648);
  ushort_t* Kb  = (ushort_t*)(ws + 67108864);
  ushort_t* Vt  = (ushort_t*)(ws + 83886080);
  float2*   fcs = (float2*)  (ws + 83886080);     // 1 MB, dead before transpose_v
  float*    O   = (float*)   (ws + 100663296);
  ushort_t* Vb  = (ushort_t*)(ws + 100663296);    // temp (first half of O region)
  float*    ak  = (float*)   (ws + 134217728);
  float*    av  = (float*)   (ws + 134299648);
  ushort_t* Ob  = Xb;

  cast_x_kernel<<<4096, 256, 0, stream>>>(x, Xb);
  rope_pack_kernel<<<512, 256, 0, stream>>>(fc, fs, fcs);
  transpose_w_kernel<<<dim3(32, 32, 4), 256, 0, stream>>>(wq, wk, wv, wo, WtQ);
  hipMemsetAsync(ak, 0, 163840, stream);
  adapter_kv_kernel<<<dim3(8, 16, 2), 256, 0, stream>>>(adapter, wk, wv, ak, av);
  gemm_qkv_kernel<<<dim3(48, 32), 256, 0, stream>>>(Xb, WtQ, Qb, Kb, Vb, fcs);
  transpose_v_kernel<<<dim3(32, 2, 32), 256, 0, stream>>>(Vb, Vt);
  flash_kernel<<<512, 256, 0, stream>>>(Qb, Kb, Vt, O);
  adapter_add_kernel<<<16384, 256, 0, stream>>>(O, Qb, ak, av, gate, Ob);
  gemm_kernel<<<dim3(16, 32), 256, 0, stream>>>(Ob, WtO, (float*)d_out, 4096, 2048, 2048);
}

// Round 5
// 457.142 us; speedup vs baseline: 1.3645x; 1.1708x over previous
//
#include <hip/hip_runtime.h>

// ---------------------------------------------------------------------------
// Attention_16698832847178: B=2,S=2048,D=2048,H=16,HD=128,L=10
// R5: revert gemm store packing (R4 regression); fuse V-transpose into
// gemm_qkv epilogue (per-wave LDS transpose); fuse adapter attention into
// flash epilogue (MFMA scores + DPP softmax + MFMA PV into normalized oacc),
// flash writes bf16 Ob directly. Kernels removed: transpose_v, adapter_add.
// ---------------------------------------------------------------------------

typedef unsigned short ushort_t;
typedef unsigned int uint32;
typedef __attribute__((ext_vector_type(8))) short bf16x8;   // 8 bf16 = 4 VGPRs
typedef __attribute__((ext_vector_type(4))) float f32x4;

__device__ __forceinline__ void async16(void* lds, const void* g) {
  __builtin_amdgcn_global_load_lds((const __attribute__((address_space(1))) void*)g,
                                   (__attribute__((address_space(3))) void*)lds,
                                   16, 0, 0);
}
__device__ __forceinline__ ushort_t f2bf(float f) {
  uint32 u = __float_as_uint(f);
  u += 0x7FFFu + ((u >> 16) & 1u);   // round-to-nearest-even
  return (ushort_t)(u >> 16);
}
__device__ __forceinline__ float bf2f(ushort_t b) {
  return __uint_as_float(((uint32)b) << 16);
}
// value from lane^1 via DPP quad_perm [1,0,3,2] (VALU, no LDS)
__device__ __forceinline__ float dpp_xor1(float v) {
  return __int_as_float(__builtin_amdgcn_update_dpp(
      0, __float_as_int(v), 0xB1, 0xf, 0xf, true));
}
#define DPP_MAX(t, ctrl) \
  t = fmaxf(t, __int_as_float(__builtin_amdgcn_update_dpp( \
      0, __float_as_int(t), (ctrl), 0xf, 0xf, true)))
#define DPP_ADD(t, ctrl) \
  t += __int_as_float(__builtin_amdgcn_update_dpp( \
      0, __float_as_int(t), (ctrl), 0xf, 0xf, true))
__device__ __forceinline__ float rowmax16(float t) {
  DPP_MAX(t, 0xB1);   // xor 1
  DPP_MAX(t, 0x4E);   // xor 2
  t = fmaxf(t, __int_as_float(__builtin_amdgcn_ds_swizzle(
      __float_as_int(t), 0x101F)));                  // xor 4
  DPP_MAX(t, 0x128);  // row_ror:8 -> xor 8 (halves uniform after xor1/2/4)
  return t;
}
__device__ __forceinline__ float rowsum16(float t) {
  DPP_ADD(t, 0xB1);
  DPP_ADD(t, 0x4E);
  t += __int_as_float(__builtin_amdgcn_ds_swizzle(__float_as_int(t), 0x101F));
  DPP_ADD(t, 0x128);
  return t;
}

// ---------------------------------------------------------------------------
// cast x (fp32) -> bf16, 8 elements/thread
__global__ __launch_bounds__(256) void cast_x_kernel(const float* __restrict__ x,
                                                     ushort_t* __restrict__ Xb) {
  size_t i = ((size_t)blockIdx.x * 256 + threadIdx.x) * 8;
  float4 a = *(const float4*)(x + i);
  float4 b = *(const float4*)(x + i + 4);
  uint4 o;
  o.x = (uint32)f2bf(a.x) | ((uint32)f2bf(a.y) << 16);
  o.y = (uint32)f2bf(a.z) | ((uint32)f2bf(a.w) << 16);
  o.z = (uint32)f2bf(b.x) | ((uint32)f2bf(b.y) << 16);
  o.w = (uint32)f2bf(b.z) | ((uint32)f2bf(b.w) << 16);
  *(uint4*)(Xb + i) = o;
}

// ---------------------------------------------------------------------------
// pack rope table: fcs[s][fi] = (cos, sin)
__global__ __launch_bounds__(256) void rope_pack_kernel(
    const float* __restrict__ fc, const float* __restrict__ fs,
    float2* __restrict__ fcs) {
  int i = blockIdx.x * 256 + threadIdx.x;   // < 131072
  fcs[i] = make_float2(fc[i], fs[i]);
}

// ---------------------------------------------------------------------------
// W[k][n] fp32 -> Wt[n][k] bf16 (64x64 tiles), dword stores
__global__ __launch_bounds__(256) void transpose_w_kernel(
    const float* __restrict__ w0, const float* __restrict__ w1,
    const float* __restrict__ w2, const float* __restrict__ w3,
    ushort_t* __restrict__ outBase) {
  const float* W = (blockIdx.z == 0) ? w0 : (blockIdx.z == 1) ? w1
                 : (blockIdx.z == 2) ? w2 : w3;
  ushort_t* Wt = outBase + (size_t)blockIdx.z * 4194304;  // 2048*2048
  __shared__ float L[64][65];
  int t = threadIdx.x, tc = t & 63, tr = t >> 6;
  int k0 = blockIdx.x * 64, n0 = blockIdx.y * 64;
  for (int i = 0; i < 16; ++i) {
    int r = i * 4 + tr;
    L[r][tc] = W[(size_t)(k0 + r) * 2048 + n0 + tc];
  }
  __syncthreads();
  int tr8 = t >> 5, tc2 = t & 31;
  for (int i = 0; i < 8; ++i) {
    int r = i * 8 + tr8;
    uint32 pk = (uint32)f2bf(L[2 * tc2][r]) | ((uint32)f2bf(L[2 * tc2 + 1][r]) << 16);
    *(uint32*)(Wt + (size_t)(n0 + r) * 2048 + k0 + 2 * tc2) = pk;
  }
}

// ---------------------------------------------------------------------------
// adapter projections: ak/av[l][n] = sum_k adapter[l][k] * W[k][n]  (fp32)
__global__ __launch_bounds__(256) void adapter_kv_kernel(
    const float* __restrict__ adapter, const float* __restrict__ wk,
    const float* __restrict__ wv, float* __restrict__ ak, float* __restrict__ av) {
  const float* W = blockIdx.z ? wv : wk;
  float* out = blockIdx.z ? av : ak;
  __shared__ float As[10][128];
  int t = threadIdx.x;
  int k0 = blockIdx.y * 128;
  for (int i = t; i < 1280; i += 256)
    As[i >> 7][i & 127] = adapter[(size_t)(i >> 7) * 2048 + k0 + (i & 127)];
  __syncthreads();
  int n = blockIdx.x * 256 + t;
  float acc[10];
#pragma unroll
  for (int l = 0; l < 10; ++l) acc[l] = 0.f;
  for (int kk = 0; kk < 128; ++kk) {
    float wv_ = W[(size_t)(k0 + kk) * 2048 + n];
#pragma unroll
    for (int l = 0; l < 10; ++l) acc[l] += As[l][kk] * wv_;
  }
#pragma unroll
  for (int l = 0; l < 10; ++l) atomicAdd(&out[l * 2048 + n], acc[l]);
}

// ---------------------------------------------------------------------------
// pack ak/av (fp32) into MFMA-fragment-friendly bf16 buffers:
// akb[h][l(16)][d(128)] (l>=10 zero), avb[h][d(128)][l(32)] (l>=10 zero)
__global__ __launch_bounds__(256) void adapter_pack_kernel(
    const float* __restrict__ ak, const float* __restrict__ av,
    ushort_t* __restrict__ akb, ushort_t* __restrict__ avb) {
  int t = blockIdx.x * 256 + threadIdx.x;   // 65536 threads
  if (t < 32768) {
    int h = t >> 11, l = (t >> 7) & 15, d = t & 127;
    akb[t] = (l < 10) ? f2bf(ak[l * 2048 + h * 128 + d]) : (ushort_t)0;
  }
  int h = t >> 12, d = (t >> 5) & 127, l = t & 31;
  avb[t] = (l < 10) ? f2bf(av[l * 2048 + h * 128 + d]) : (ushort_t)0;
}

// ---------------------------------------------------------------------------
// Fused QKV GEMM: C[4096, 6144] = Xb[4096,2048] x WtQKV[6144,2048]^T.
// Q,K segments: RoPE fused, bf16 out. V segment: per-wave LDS transpose,
// writes Vt (B,H,HD,S) directly.
__global__ __launch_bounds__(256) void gemm_qkv_kernel(
    const ushort_t* __restrict__ A, const ushort_t* __restrict__ Bt,
    ushort_t* __restrict__ outQ, ushort_t* __restrict__ outK,
    ushort_t* __restrict__ Vt,
    const float2* __restrict__ fcs) {
  __shared__ char lds[32768];
  char* ldsA = lds;
  char* ldsB = lds + 16384;
  const int tid = threadIdx.x;
  const int w = tid >> 6, lane = tid & 63, quad = lane >> 4, l15 = lane & 15;
  const int wm = (w >> 1) * 64, wn = (w & 1) * 64;
  const size_t bm0 = (size_t)blockIdx.y * 128, bn0 = (size_t)blockIdx.x * 128;
  const int K = 2048;

  f32x4 zero4 = {0.f, 0.f, 0.f, 0.f};
  f32x4 acc[4][4];
#pragma unroll
  for (int i = 0; i < 4; ++i)
#pragma unroll
    for (int j = 0; j < 4; ++j) acc[i][j] = zero4;

  const int rS = w * 32;
  const int rowOff = lane >> 3;
  const int cph = lane & 7;

  for (int kt = 0; kt < K; kt += 64) {
#pragma unroll
    for (int i = 0; i < 4; ++i) {
      int r0 = rS + i * 8;
      int row = r0 + rowOff;
      int cl = cph ^ (row & 7);
      async16(ldsA + r0 * 128, A + (bm0 + row) * (size_t)K + kt + cl * 8);
      async16(ldsB + r0 * 128, Bt + (bn0 + row) * (size_t)K + kt + cl * 8);
    }
    __syncthreads();
#pragma unroll
    for (int ks = 0; ks < 2; ++ks) {
      bf16x8 af[4], bfv[4];
      int ch = ks * 4 + quad;
#pragma unroll
      for (int tt = 0; tt < 4; ++tt) {
        int ra = wm + tt * 16 + l15;
        af[tt] = *(const bf16x8*)(ldsA + ra * 128 + ((ch ^ (ra & 7)) * 16));
        int rb = wn + tt * 16 + l15;
        bfv[tt] = *(const bf16x8*)(ldsB + rb * 128 + ((ch ^ (rb & 7)) * 16));
      }
#pragma unroll
      for (int i = 0; i < 4; ++i)
#pragma unroll
        for (int j = 0; j < 4; ++j)
          acc[i][j] = __builtin_amdgcn_mfma_f32_16x16x32_bf16(af[i], bfv[j], acc[i][j], 0, 0, 0);
    }
    __syncthreads();
  }

  const int seg = (int)(bn0 >> 11);           // 0=Q, 1=K, 2=V
  if (seg < 2) {
    ushort_t* ob = (seg == 0) ? outQ : outK;
#pragma unroll
    for (int i = 0; i < 4; ++i)
#pragma unroll
      for (int r = 0; r < 4; ++r) {
        size_t m = bm0 + wm + i * 16 + quad * 4 + r;
        int s = (int)(m & 2047);
#pragma unroll
        for (int j = 0; j < 4; ++j) {
          size_t ngl = bn0 + wn + j * 16 + l15;
          size_t n = ngl & 2047;
          float v = acc[i][j][r];
          float v2 = dpp_xor1(v);             // RoPE pair partner (col n^1)
          int fi = ((int)n & 127) >> 1;
          float2 cs = fcs[s * 64 + fi];
          v = (lane & 1) ? (v2 * cs.y + v * cs.x) : (v * cs.x - v2 * cs.y);
          ob[m * 2048 + n] = f2bf(v);
        }
      }
  } else {
    // V segment: per-wave 64x64 transpose through LDS, write Vt[bh][d][s].
    // Wave patch T (8KB at lds + w*8192): row nn (64), 32 dwords/row,
    // dword slot swizzled: pd = md ^ (nn & 31), mm = 2*md + sub.
    char* T = lds + w * 8192;
#pragma unroll
    for (int i = 0; i < 4; ++i)
#pragma unroll
      for (int j = 0; j < 4; ++j) {
        int nn = j * 16 + l15;
        int md0 = i * 8 + quad * 2;
        uint32 p01 = (uint32)f2bf(acc[i][j][0]) | ((uint32)f2bf(acc[i][j][1]) << 16);
        uint32 p23 = (uint32)f2bf(acc[i][j][2]) | ((uint32)f2bf(acc[i][j][3]) << 16);
        *(uint32*)(T + nn * 128 + ((md0 ^ (nn & 31)) * 4)) = p01;
        *(uint32*)(T + nn * 128 + (((md0 + 1) ^ (nn & 31)) * 4)) = p23;
      }
    // read + coalesced global store (per-wave private patch: no barrier)
    const int bh = (int)((bm0 >> 11) * 16 + ((bn0 & 2047) >> 7));
    const int p = lane & 31;
#pragma unroll
    for (int it = 0; it < 32; ++it) {
      int row = it * 2 + (lane >> 5);
      uint32 dv = *(const uint32*)(T + row * 128 + p * 4);
      int md = p ^ (row & 31);
      size_t d = (size_t)(wn + row);
      size_t s = (bm0 & 2047) + wm + 2 * md;
      *(uint32*)(Vt + ((size_t)bh * 128 + d) * 2048 + s) = dv;
    }
  }
}

// ---------------------------------------------------------------------------
// Generic GEMM (fp32 out) for the output projection.
__global__ __launch_bounds__(256) void gemm_kernel(
    const ushort_t* __restrict__ A, const ushort_t* __restrict__ Bt,
    float* __restrict__ out, int M, int N, int K) {
  __shared__ char ldsA[16384];
  __shared__ char ldsB[16384];
  const int tid = threadIdx.x;
  const int w = tid >> 6, lane = tid & 63, quad = lane >> 4, l15 = lane & 15;
  const int wm = (w >> 1) * 64, wn = (w & 1) * 64;
  const size_t bm0 = (size_t)blockIdx.y * 128, bn0 = (size_t)blockIdx.x * 128;

  f32x4 zero4 = {0.f, 0.f, 0.f, 0.f};
  f32x4 acc[4][4];
#pragma unroll
  for (int i = 0; i < 4; ++i)
#pragma unroll
    for (int j = 0; j < 4; ++j) acc[i][j] = zero4;

  const int rS = w * 32;
  const int rowOff = lane >> 3;
  const int cph = lane & 7;

  for (int kt = 0; kt < K; kt += 64) {
#pragma unroll
    for (int i = 0; i < 4; ++i) {
      int r0 = rS + i * 8;
      int row = r0 + rowOff;
      int cl = cph ^ (row & 7);
      async16(ldsA + r0 * 128, A + (bm0 + row) * (size_t)K + kt + cl * 8);
      async16(ldsB + r0 * 128, Bt + (bn0 + row) * (size_t)K + kt + cl * 8);
    }
    __syncthreads();
#pragma unroll
    for (int ks = 0; ks < 2; ++ks) {
      bf16x8 af[4], bfv[4];
      int ch = ks * 4 + quad;
#pragma unroll
      for (int tt = 0; tt < 4; ++tt) {
        int ra = wm + tt * 16 + l15;
        af[tt] = *(const bf16x8*)(ldsA + ra * 128 + ((ch ^ (ra & 7)) * 16));
        int rb = wn + tt * 16 + l15;
        bfv[tt] = *(const bf16x8*)(ldsB + rb * 128 + ((ch ^ (rb & 7)) * 16));
      }
#pragma unroll
      for (int i = 0; i < 4; ++i)
#pragma unroll
        for (int j = 0; j < 4; ++j)
          acc[i][j] = __builtin_amdgcn_mfma_f32_16x16x32_bf16(af[i], bfv[j], acc[i][j], 0, 0, 0);
    }
    __syncthreads();
  }
#pragma unroll
  for (int i = 0; i < 4; ++i)
#pragma unroll
    for (int r = 0; r < 4; ++r) {
      size_t m = bm0 + wm + i * 16 + quad * 4 + r;
#pragma unroll
      for (int j = 0; j < 4; ++j) {
        size_t n = bn0 + wn + j * 16 + l15;
        out[m * N + n] = acc[i][j][r];
      }
    }
}

// ---------------------------------------------------------------------------
// Flash attention, causal, + fused adapter attention. 256 threads, q-tile 128,
// k-tile 64. LDS 48KB. Balanced static qt per CU ({u,15-u} pairs).
// Epilogue: normalize oacc, then oacc += (gate*softmax(Q ak^T))@av via MFMA;
// writes bf16 Ob directly.
__global__ __launch_bounds__(256) void flash_kernel(
    const ushort_t* __restrict__ Qb, const ushort_t* __restrict__ Kb,
    const ushort_t* __restrict__ Vt, const ushort_t* __restrict__ akb,
    const ushort_t* __restrict__ avb, const float* __restrict__ gate,
    ushort_t* __restrict__ Ob) {
  __shared__ char ldsK[16384];   // 64 tok x 256B, chunk swz ^(row&15)
  __shared__ char ldsV[16384];   // 128 d x 128B, chunk swz ^(dr&7)
  __shared__ char ldsP[16384];   // loop: P 128q x 128B swz; epilogue: pa[128][40]
  const int tid = threadIdx.x;
  const int w = tid >> 6, lane = tid & 63, quad = lane >> 4, l15 = lane & 15;
  const int idx = blockIdx.x;
  const int p = idx >> 8, c = idx & 255;
  const int u = c >> 4, vv = c & 15;
  const int qt = p ? (15 - u) : u;
  const int hb = (p << 4) | vv;
  const int h = hb >> 1, b = hb & 1;
  const float scale = 0.08838834764831845f;  // 1/sqrt(128)

  bf16x8 ones;
#pragma unroll
  for (int j = 0; j < 8; ++j) ones[j] = (short)0x3F80;

  // Q fragments in registers: 2 m-tiles x 4 d-steps (wave rows w*32..+31)
  bf16x8 qf[2][4];
#pragma unroll
  for (int mt = 0; mt < 2; ++mt) {
    size_t qrow = (size_t)qt * 128 + w * 32 + mt * 16 + l15;
    const ushort_t* base = Qb + ((size_t)b * 2048 + qrow) * 2048 + h * 128 + quad * 8;
#pragma unroll
    for (int ds = 0; ds < 4; ++ds) qf[mt][ds] = *(const bf16x8*)(base + ds * 32);
  }

  f32x4 zero4 = {0.f, 0.f, 0.f, 0.f};
  f32x4 oacc[2][8];
  f32x4 osum[2];
  float mrow[2][4];
#pragma unroll
  for (int mt = 0; mt < 2; ++mt) {
#pragma unroll
    for (int n8 = 0; n8 < 8; ++n8) oacc[mt][n8] = zero4;
    osum[mt] = zero4;
#pragma unroll
    for (int r = 0; r < 4; ++r) mrow[mt][r] = -1e30f;
  }

  const int ktmax = 2 * qt + 1;
  for (int kt = 0; kt <= ktmax; ++kt) {
#pragma unroll
    for (int ii = 0; ii < 4; ++ii) {
      int r0 = w * 16 + ii * 4;
      int row = r0 + (lane >> 4);
      int cl = (lane & 15) ^ (row & 15);
      async16(ldsK + r0 * 256,
              Kb + ((size_t)b * 2048 + kt * 64 + row) * 2048 + h * 128 + cl * 8);
    }
#pragma unroll
    for (int ii = 0; ii < 4; ++ii) {
      int d0 = w * 32 + ii * 8;
      int dr = d0 + (lane >> 3);
      int cl = (lane & 7) ^ (dr & 7);
      async16(ldsV + d0 * 128,
              Vt + ((size_t)(b * 16 + h) * 128 + dr) * 2048 + kt * 64 + cl * 8);
    }
    __syncthreads();

    // S = Q K^T
    f32x4 sacc[2][4];
#pragma unroll
    for (int mt = 0; mt < 2; ++mt)
#pragma unroll
      for (int nt = 0; nt < 4; ++nt) sacc[mt][nt] = zero4;
#pragma unroll
    for (int ds = 0; ds < 4; ++ds) {
      bf16x8 kf[4];
      int ch = ds * 4 + quad;
#pragma unroll
      for (int nt = 0; nt < 4; ++nt) {
        int row = nt * 16 + l15;
        kf[nt] = *(const bf16x8*)(ldsK + row * 256 + ((ch ^ (row & 15)) * 16));
      }
#pragma unroll
      for (int mt = 0; mt < 2; ++mt)
#pragma unroll
        for (int nt = 0; nt < 4; ++nt)
          sacc[mt][nt] = __builtin_amdgcn_mfma_f32_16x16x32_bf16(qf[mt][ds], kf[nt], sacc[mt][nt], 0, 0, 0);
    }

    // online softmax
    const bool domask = (kt >= 2 * qt);
#pragma unroll
    for (int mt = 0; mt < 2; ++mt) {
      float tmax[4] = {-1e30f, -1e30f, -1e30f, -1e30f};
      const int qbase = qt * 128 + w * 32 + mt * 16 + quad * 4;
#pragma unroll
      for (int nt = 0; nt < 4; ++nt) {
        int kg = kt * 64 + nt * 16 + l15;
#pragma unroll
        for (int r = 0; r < 4; ++r) {
          float s = sacc[mt][nt][r] * scale;
          if (domask && kg > qbase + r) s = -1e30f;
          sacc[mt][nt][r] = s;
          tmax[r] = fmaxf(tmax[r], s);
        }
      }
#pragma unroll
      for (int r = 0; r < 4; ++r) {
        float t = rowmax16(tmax[r]);
        float mnew = fmaxf(mrow[mt][r], t);
        float alpha = __expf(mrow[mt][r] - mnew);
        mrow[mt][r] = mnew;
        osum[mt][r] *= alpha;
#pragma unroll
        for (int n8 = 0; n8 < 8; ++n8) oacc[mt][n8][r] *= alpha;
        tmax[r] = mnew;
      }
#pragma unroll
      for (int nt = 0; nt < 4; ++nt) {
        int col = nt * 16 + l15;
#pragma unroll
        for (int r = 0; r < 4; ++r) {
          float pv = __expf(sacc[mt][nt][r] - tmax[r]);
          int prow = w * 32 + mt * 16 + quad * 4 + r;
          int addr = prow * 128 + (((col >> 3) ^ (prow & 7)) * 16) + (col & 7) * 2;
          *(ushort_t*)(ldsP + addr) = f2bf(pv);
        }
      }
    }

    // O += P V ; osum += P 1
#pragma unroll
    for (int ks = 0; ks < 2; ++ks) {
      int ch = ks * 4 + quad;
      bf16x8 pf[2];
#pragma unroll
      for (int mt = 0; mt < 2; ++mt) {
        int prow = w * 32 + mt * 16 + l15;
        pf[mt] = *(const bf16x8*)(ldsP + prow * 128 + ((ch ^ (prow & 7)) * 16));
      }
#pragma unroll
      for (int mt = 0; mt < 2; ++mt)
        osum[mt] = __builtin_amdgcn_mfma_f32_16x16x32_bf16(pf[mt], ones, osum[mt], 0, 0, 0);
#pragma unroll
      for (int n8 = 0; n8 < 8; ++n8) {
        int dr = n8 * 16 + l15;
        bf16x8 vf = *(const bf16x8*)(ldsV + dr * 128 + ((ch ^ (dr & 7)) * 16));
#pragma unroll
        for (int mt = 0; mt < 2; ++mt)
          oacc[mt][n8] = __builtin_amdgcn_mfma_f32_16x16x32_bf16(pf[mt], vf, oacc[mt][n8], 0, 0, 0);
      }
    }
    __syncthreads();
  }

  // ---------------- fused adapter epilogue ----------------
  // a_scores = Q akb^T (MFMA), softmax over l (16-lane DPP, cols>=10 masked),
  // probs pre-scaled by gate/asum -> pa (ldsP, stride 40 elems), then
  // oacc_norm += pa @ avb via MFMA. All pa traffic is same-wave rows.
  const float g = gate[h];
  // zero pa cols k=16..31 of this wave's rows (lds reuse after final barrier)
  {
    int row = w * 32 + (lane >> 1);
    int koff = 16 + (lane & 1) * 8;
    *(uint4*)(ldsP + row * 80 + koff * 2) = make_uint4(0, 0, 0, 0);
  }
  f32x4 sa[2] = {zero4, zero4};
#pragma unroll
  for (int ds = 0; ds < 4; ++ds) {
    bf16x8 kfa = *(const bf16x8*)(akb + ((size_t)h * 16 + l15) * 128 + ds * 32 + quad * 8);
#pragma unroll
    for (int mt = 0; mt < 2; ++mt)
      sa[mt] = __builtin_amdgcn_mfma_f32_16x16x32_bf16(qf[mt][ds], kfa, sa[mt], 0, 0, 0);
  }
#pragma unroll
  for (int mt = 0; mt < 2; ++mt) {
#pragma unroll
    for (int r = 0; r < 4; ++r) {
      float s = sa[mt][r] * scale;
      if (l15 >= 10) s = -1e30f;
      float mx = rowmax16(s);
      float e = __expf(s - mx);
      float sum = rowsum16(e);
      float pv = g * e / sum;
      int row = w * 32 + mt * 16 + quad * 4 + r;
      *(ushort_t*)(ldsP + row * 80 + l15 * 2) = f2bf(pv);
    }
  }
  bf16x8 paf[2];
#pragma unroll
  for (int mt = 0; mt < 2; ++mt)
    paf[mt] = *(const bf16x8*)(ldsP + (w * 32 + mt * 16 + l15) * 80 + quad * 16);

  // normalize main attention
#pragma unroll
  for (int mt = 0; mt < 2; ++mt) {
    float rl[4];
#pragma unroll
    for (int r = 0; r < 4; ++r) rl[r] = 1.f / osum[mt][r];
#pragma unroll
    for (int n8 = 0; n8 < 8; ++n8)
#pragma unroll
      for (int r = 0; r < 4; ++r) oacc[mt][n8][r] *= rl[r];
  }
  // += pa @ avb ; store bf16
#pragma unroll
  for (int n8 = 0; n8 < 8; ++n8) {
    bf16x8 avf = *(const bf16x8*)(avb + ((size_t)h * 128 + n8 * 16 + l15) * 32 + quad * 8);
#pragma unroll
    for (int mt = 0; mt < 2; ++mt)
      oacc[mt][n8] = __builtin_amdgcn_mfma_f32_16x16x32_bf16(paf[mt], avf, oacc[mt][n8], 0, 0, 0);
  }
#pragma unroll
  for (int mt = 0; mt < 2; ++mt) {
    size_t qb0 = (size_t)qt * 128 + w * 32 + mt * 16 + quad * 4;
#pragma unroll
    for (int n8 = 0; n8 < 8; ++n8) {
      size_t col = (size_t)h * 128 + n8 * 16 + l15;
#pragma unroll
      for (int r = 0; r < 4; ++r)
        Ob[((size_t)b * 2048 + qb0 + r) * 2048 + col] = f2bf(oacc[mt][n8][r]);
    }
  }
}

// ---------------------------------------------------------------------------
extern "C" void kernel_launch(void* const* d_in, const int* in_sizes, int n_in,
                              void* d_out, int out_size, void* d_ws, size_t ws_size,
                              hipStream_t stream) {
  (void)in_sizes; (void)n_in; (void)out_size; (void)ws_size;
  const float* x       = (const float*)d_in[0];
  const float* wq      = (const float*)d_in[1];
  const float* wk      = (const float*)d_in[2];
  const float* wv      = (const float*)d_in[3];
  const float* wo      = (const float*)d_in[4];
  const float* adapter = (const float*)d_in[5];
  const float* gate    = (const float*)d_in[6];
  const float* fc      = (const float*)d_in[7];
  const float* fs      = (const float*)d_in[8];

  char* ws = (char*)d_ws;
  ushort_t* Xb   = (ushort_t*)(ws + 0);           // 16 MB (reused as Ob)
  ushort_t* WtQ  = (ushort_t*)(ws + 16777216);    // 8 MB x4 contiguous
  ushort_t* WtO  = (ushort_t*)(ws + 41943040);
  ushort_t* Qb   = (ushort_t*)(ws + 50331648);    // 16 MB
  ushort_t* Kb   = (ushort_t*)(ws + 67108864);    // 16 MB
  ushort_t* Vt   = (ushort_t*)(ws + 83886080);    // 16 MB
  float*    ak   = (float*)   (ws + 100663296);   // 80 KB
  float*    av   = (float*)   (ws + 100745216);   // 80 KB
  ushort_t* akb  = (ushort_t*)(ws + 100827136);   // 64 KB
  ushort_t* avb  = (ushort_t*)(ws + 100892672);   // 128 KB
  float2*   fcs  = (float2*)  (ws + 101023744);   // 1 MB
  ushort_t* Ob   = Xb;

  cast_x_kernel<<<4096, 256, 0, stream>>>(x, Xb);
  rope_pack_kernel<<<512, 256, 0, stream>>>(fc, fs, fcs);
  transpose_w_kernel<<<dim3(32, 32, 4), 256, 0, stream>>>(wq, wk, wv, wo, WtQ);
  hipMemsetAsync(ak, 0, 163840, stream);
  adapter_kv_kernel<<<dim3(8, 16, 2), 256, 0, stream>>>(adapter, wk, wv, ak, av);
  adapter_pack_kernel<<<256, 256, 0, stream>>>(ak, av, akb, avb);
  gemm_qkv_kernel<<<dim3(48, 32), 256, 0, stream>>>(Xb, WtQ, Qb, Kb, Vt, fcs);
  flash_kernel<<<512, 256, 0, stream>>>(Qb, Kb, Vt, akb, avb, gate, Ob);
  gemm_kernel<<<dim3(16, 32), 256, 0, stream>>>(Ob, WtO, (float*)d_out, 4096, 2048, 2048);
}